// Round 1
// baseline (304.342 us; speedup 1.0000x reference)
//
#include <hip/hip_runtime.h>

#define D_MODEL 1024
#define NH 16
#define DH 64
#define BB 4
#define LQ 512
#define LK 4096

typedef __attribute__((ext_vector_type(8))) short bf16x8;
typedef __attribute__((ext_vector_type(4))) short bf16x4;
typedef __attribute__((ext_vector_type(4))) float f32x4;
typedef __attribute__((ext_vector_type(4))) unsigned short us4;

union U4 { unsigned int u[2]; bf16x4 v; };
union U8 { unsigned int u[4]; bf16x8 v; };

#define MFMA32(a, b, c) __builtin_amdgcn_mfma_f32_16x16x32_bf16(a, b, c, 0, 0, 0)

#if __has_builtin(__builtin_amdgcn_mfma_f32_16x16x16bf16_1k)
#define HAVE_MFMA16 1
#define MFMA16(a, b, c) __builtin_amdgcn_mfma_f32_16x16x16bf16_1k(a, b, c, 0, 0, 0)
#else
#define HAVE_MFMA16 0
#endif

#if __has_builtin(__builtin_amdgcn_exp2f)
#define EXP2F __builtin_amdgcn_exp2f
#else
__device__ __forceinline__ float EXP2F(float x) { return __expf(x * 0.69314718056f); }
#endif

// Pipeline barriers: top waits only the previous tile's load batch (keeps next in
// flight); end barrier has NO vmcnt drain (the m97 stall never executes).
#define PIPE_BAR(KEEP) asm volatile("s_waitcnt vmcnt(" #KEEP ") lgkmcnt(0)\n\ts_barrier" ::: "memory")
#define END_BAR()      asm volatile("s_waitcnt lgkmcnt(0)\n\ts_barrier" ::: "memory")

__device__ __forceinline__ unsigned short f2bf(float f) {
    unsigned int u = __float_as_uint(f);
    u += 0x7fffu + ((u >> 16) & 1u);   // RNE
    return (unsigned short)(u >> 16);
}
__device__ __forceinline__ unsigned int packrn(float a, float b) {
    unsigned int ua = __float_as_uint(a) + 0x8000u;
    unsigned int ub = __float_as_uint(b) + 0x8000u;
    return __builtin_amdgcn_perm(ub, ua, 0x07060302u);
}
__device__ __forceinline__ void gld16(const void* g, void* l) {
    __builtin_amdgcn_global_load_lds(
        (__attribute__((address_space(1))) void*)(g),
        (__attribute__((address_space(3))) void*)(l), 16, 0, 0);
}
__device__ __forceinline__ unsigned int bperm(int srclane4, unsigned int v) {
    return (unsigned int)__builtin_amdgcn_ds_bpermute(srclane4, (int)v);
}

// ---------------- all fp32 -> bf16 converts, one launch ----------------
__global__ __launch_bounds__(256) void cvt_all(const float* __restrict__ q,
                                               const float* __restrict__ mem,
                                               const float* __restrict__ w0, const float* __restrict__ w1,
                                               const float* __restrict__ w2, const float* __restrict__ w3,
                                               unsigned short* __restrict__ dst) {
    constexpr size_t EQ = (size_t)BB * LQ * D_MODEL;
    constexpr size_t EM = (size_t)BB * LK * D_MODEL;
    constexpr size_t EW = (size_t)D_MODEL * D_MODEL;
    constexpr size_t R1 = EQ + EM;
    size_t i = ((size_t)blockIdx.x * 256 + threadIdx.x) * 4;
    const float* s; size_t o;
    if (i < EQ)                { s = q;   o = i; }
    else if (i < R1)           { s = mem; o = i - EQ; }
    else if (i < R1 + EW)      { s = w0;  o = i - R1; }
    else if (i < R1 + 2 * EW)  { s = w1;  o = i - R1 - EW; }
    else if (i < R1 + 3 * EW)  { s = w2;  o = i - R1 - 2 * EW; }
    else                       { s = w3;  o = i - R1 - 3 * EW; }
    float4 v = *(const float4*)(s + o);
    us4 ob;
    ob.x = f2bf(v.x); ob.y = f2bf(v.y); ob.z = f2bf(v.z); ob.w = f2bf(v.w);
    *(us4*)(dst + i) = ob;
}

// -------- shared GEMM-core macros: 128x128 tile, BK=64, 4 waves, dbuf pipeline --------
// (kept for proj_q + gemm_o; the heavy K/V projections now use the 256^2 8-phase kernel)
#define GEMM_DECLS                                                                 \
    const int tid = threadIdx.x;                                                   \
    const int w = tid >> 6, lane = tid & 63;                                       \
    const int wr = (w >> 1) * 64, wc = (w & 1) * 64;                               \
    const int srow = lane >> 3, ssw = ((lane & 7) ^ srow) * 8;                     \
    const int fr = lane & 15, g = lane >> 4, frx = fr & 7;                         \
    f32x4 zero = {0.f, 0.f, 0.f, 0.f};                                             \
    f32x4 acc[4][4];                                                               \
    for (int i = 0; i < 4; ++i)                                                    \
        for (int j = 0; j < 4; ++j) acc[i][j] = zero;                              \
    const unsigned short* ga = A + (size_t)(m0 + w * 32 + srow) * 1024 + ssw;      \
    const unsigned short* gb = Bw + (size_t)(n0 + w * 32 + srow) * 1024 + ssw;     \
    unsigned short* la = As + (w * 32 + srow * 0) * 64 + (w * 32) * 0;             \
    (void)la;

#define GEMM_ISSUE(PAR) do {                                                       \
    unsigned short* da = As + (PAR) * (128 * 64) + (w * 32) * 64;                  \
    unsigned short* db = Bs + (PAR) * (128 * 64) + (w * 32) * 64;                  \
    for (int c = 0; c < 4; ++c) {                                                  \
        gld16(ga + (size_t)c * 8 * 1024, da + c * 8 * 64);                         \
        gld16(gb + (size_t)c * 8 * 1024, db + c * 8 * 64);                         \
    }                                                                              \
    ga += 64; gb += 64;                                                            \
} while (0)

#define GEMM_COMPUTE(PAR) do {                                                     \
    const unsigned short* Ap = As + (PAR) * (128 * 64);                            \
    const unsigned short* Bp = Bs + (PAR) * (128 * 64);                            \
    for (int ks = 0; ks < 2; ++ks) {                                               \
        const int fx = ((ks * 4 + g) ^ frx) * 8;                                   \
        bf16x8 af[4], bfr[4];                                                      \
        for (int i = 0; i < 4; ++i) af[i] = *(const bf16x8*)(Ap + (wr + 16 * i + fr) * 64 + fx); \
        for (int j = 0; j < 4; ++j) bfr[j] = *(const bf16x8*)(Bp + (wc + 16 * j + fr) * 64 + fx); \
        for (int i = 0; i < 4; ++i)                                                \
            for (int j = 0; j < 4; ++j)                                            \
                acc[i][j] = MFMA32(af[i], bfr[j], acc[i][j]);                      \
    }                                                                              \
} while (0)

#define GEMM_PIPELINE                                                              \
    GEMM_ISSUE(0); GEMM_ISSUE(1);                                                  \
    for (int it = 0; it < 14; ++it) {                                              \
        PIPE_BAR(8);                                                               \
        GEMM_COMPUTE(it & 1);                                                      \
        END_BAR();                                                                 \
        GEMM_ISSUE(it & 1);                                                        \
    }                                                                              \
    PIPE_BAR(8);                                                                   \
    GEMM_COMPUTE(0);                                                               \
    PIPE_BAR(0);                                                                   \
    GEMM_COMPUTE(1);

// ================== 256x256-tile 8-phase GEMM for K/V projections ==================
// 8 waves (2M x 4N), per-wave output 128x64 (acc[8][4] f32x4 = 128 VGPR).
// LDS: per operand a 4-slot ring of [256 rows][32 K] bf16 (16 KB/slot) -> 128 KiB.
// K-tile t = K-halves h=2t,2t+1 living in slots h&3 (so tile parity picks slots 0,1 / 2,3).
// Phase p of tile t: {ds_read frag subtile; issue ONE 16KB piece; s_barrier;
//                     setprio(1); 16 MFMA; setprio(0); [vmcnt(4) at p=4]; s_barrier}
// Issue schedule (max-depth race-free for this ring; every overwrite barrier-separated
// from its slot's last read):
//   p1: A-kh1(t+1)   p2: B-kh1(t+1)   p3: A-kh0(t+2)   p4: B-kh0(t+2) + vmcnt(4)
// vmcnt(4) at tile end leaves exactly the 2 newest pieces (4 loads) in flight and
// guarantees ALL pieces of tile t+1 have landed -> never drains to 0 in the loop.
// Swizzle: LDS(row, chunk) holds Global(row, chunk ^ ((row>>1)&3)) (chunk = 8-elem
// group of the 32-K piece). ds_read_b128 then lands at the 8-dword/bank floor
// (2 lanes/bank aliasing = free, m136); gld16 dest stays linear (guide rule 21).
#define SLOT_SH 8192  /* shorts per slot: 256*32 */

#define STAGE2(GB, LB, S, H) do {                                                  \
    const unsigned short* gs_ = (GB) + (size_t)(H) * 32;                           \
    unsigned short* ld_ = (LB) + (S) * SLOT_SH + tid * 8;                          \
    gld16(gs_, ld_);                                                               \
    gld16(gs_ + (size_t)131072, ld_ + 4096);  /* +128 rows / second half */        \
} while (0)

#define PH(SLOT, I0, RB, ISSUE, TW) do {                                           \
    const unsigned short* Ap_ = As + (size_t)(SLOT) * SLOT_SH;                     \
    const unsigned short* Bp_ = Bs + (size_t)(SLOT) * SLOT_SH;                     \
    bf16x8 af_[4];                                                                 \
    _Pragma("unroll")                                                              \
    for (int ii = 0; ii < 4; ++ii)                                                 \
        af_[ii] = *(const bf16x8*)(Ap_ + aoff + ((I0) + ii) * 512);                \
    if (RB) {                                                                      \
        _Pragma("unroll")                                                          \
        for (int jj = 0; jj < 4; ++jj)                                             \
            bfh[jj] = *(const bf16x8*)(Bp_ + boff + jj * 512);                     \
    }                                                                              \
    ISSUE;                                                                         \
    asm volatile("s_barrier" ::: "memory");                                        \
    __builtin_amdgcn_s_setprio(1);                                                 \
    _Pragma("unroll")                                                              \
    for (int ii = 0; ii < 4; ++ii) {                                               \
        _Pragma("unroll")                                                          \
        for (int jj = 0; jj < 4; ++jj)                                             \
            acc[(I0) + ii][jj] = MFMA32(af_[ii], bfh[jj], acc[(I0) + ii][jj]);     \
    }                                                                              \
    __builtin_amdgcn_s_setprio(0);                                                 \
    TW;                                                                            \
    asm volatile("s_barrier" ::: "memory");                                        \
} while (0)

#define TILE8(S0, ISS1, ISS2, ISS3, ISS4, TW4) do {                                \
    bf16x8 bfh[4];                                                                 \
    PH((S0),     0, true,  ISS1, ;);                                               \
    PH((S0),     4, false, ISS2, ;);                                               \
    PH((S0) + 1, 0, true,  ISS3, ;);                                               \
    PH((S0) + 1, 4, false, ISS4, TW4);                                             \
} while (0)

__global__ __launch_bounds__(512, 2) void proj256(const unsigned short* __restrict__ memb,
                                                  const unsigned short* __restrict__ W,  // wqb base: Wq|Wk|Wv|Wo
                                                  unsigned short* __restrict__ Kp,
                                                  unsigned short* __restrict__ Vt) {
    __shared__ alignas(16) unsigned short As[4 * SLOT_SH];   // 64 KiB
    __shared__ alignas(16) unsigned short Bs[4 * SLOT_SH];   // 64 KiB
    const int x = blockIdx.x;                     // 512 blocks, exactly 1/CU (128 KiB LDS), 2 waves of blocks
    const int wg = ((x & 7) << 6) | (x >> 3);     // bijective XCD chunking (m204, nwg=512): 64 wg/XCD
    const int isV = wg >> 8;                      // [0,256): K-proj, [256,512): V-proj
    const int mt = wg & 63, nt = (wg >> 6) & 3;   // per XCD: one full 256-col weight strip (512 KB, L2-hot)
    const int m0 = mt * 256, n0 = nt * 256;
    const unsigned short* Bw = W + ((size_t)(1 + isV) << 20);  // Wk / Wv

    const int tid = threadIdx.x;
    const int lane = tid & 63, wid = tid >> 6;
    const int wm = wid >> 2, wn = wid & 3;
    const int fr = lane & 15, g = lane >> 4;
    const int sfr = (fr >> 1) & 3;                                   // swizzle bits for frag rows
    const int aoff = (wm * 128 + fr) * 32 + ((g ^ sfr) << 3);        // shorts into an A slot
    const int boff = (wn * 64 + fr) * 32 + ((g ^ sfr) << 3);         // shorts into a B slot

    f32x4 zero = {0.f, 0.f, 0.f, 0.f};
    f32x4 acc[8][4];
#pragma unroll
    for (int i = 0; i < 8; ++i)
#pragma unroll
        for (int j = 0; j < 4; ++j) acc[i][j] = zero;

    // staging addressing: thread covers rows (tid>>2) and (tid>>2)+128 of a piece,
    // 8-elem chunk (tid&3), with the inverse swizzle applied on the GLOBAL side.
    const int srow = tid >> 2;
    const int scg = (tid & 3) ^ ((tid >> 3) & 3);
    const unsigned short* gA = memb + (size_t)(m0 + srow) * 1024 + scg * 8;
    const unsigned short* gB = Bw + (size_t)(n0 + srow) * 1024 + scg * 8;

    // prologue: pieces h=0..5 (tile0 complete + kh0 of tile1), then vmcnt(4):
    // oldest 8 loads (tile 0) landed, kh0(t1) pieces stay in flight.
    STAGE2(gA, As, 0, 0); STAGE2(gB, Bs, 0, 0);
    STAGE2(gA, As, 1, 1); STAGE2(gB, Bs, 1, 1);
    STAGE2(gA, As, 2, 2); STAGE2(gB, Bs, 2, 2);
    asm volatile("s_waitcnt vmcnt(4)" ::: "memory");
    asm volatile("s_barrier" ::: "memory");

    for (int t = 0; t < 14; ++t) {                 // K=1024 -> 16 tiles; 14 uniform + 2 peeled
        const int s0 = (t & 1) * 2;
        const int h1 = 2 * t + 3, h0 = 2 * t + 4;
        const int sn1 = h1 & 3, sn0 = h0 & 3;
        TILE8(s0,
              STAGE2(gA, As, sn1, h1),
              STAGE2(gB, Bs, sn1, h1),
              STAGE2(gA, As, sn0, h0),
              STAGE2(gB, Bs, sn0, h0),
              asm volatile("s_waitcnt vmcnt(4)" ::: "memory"));
    }
    // t = 14: only kh1(15) left to issue; vmcnt(4) completes kh0(15).
    TILE8(0,
          STAGE2(gA, As, 3, 31),
          STAGE2(gB, Bs, 3, 31),
          ;, ;,
          asm volatile("s_waitcnt vmcnt(4)" ::: "memory"));
    // t = 15: drain kh1(15) after phase 2 (the only mid-tile wait, once per kernel).
    {
        bf16x8 bfh[4];
        PH(2, 0, true,  ;, ;);
        PH(2, 4, false, ;, asm volatile("s_waitcnt vmcnt(0)" ::: "memory"));
        PH(3, 0, true,  ;, ;);
        PH(3, 4, false, ;, ;);
    }

    // epilogue (same verified C/D mapping as the 128^2 kernel)
    const int cl = fr;
    if (!isV) {
#pragma unroll
        for (int i = 0; i < 8; ++i)
#pragma unroll
            for (int j = 0; j < 4; ++j)
#pragma unroll
                for (int r = 0; r < 4; ++r) {
                    int m = m0 + wm * 128 + 16 * i + g * 4 + r;
                    int n = n0 + wn * 64 + 16 * j + cl;
                    Kp[(size_t)m * 1024 + n] = f2bf(acc[i][j][r]);
                }
    } else {
#pragma unroll
        for (int i = 0; i < 8; ++i)
#pragma unroll
            for (int j = 0; j < 4; ++j)
#pragma unroll
                for (int r = 0; r < 4; ++r) {
                    int m = m0 + wm * 128 + 16 * i + g * 4 + r;
                    int n = n0 + wn * 64 + 16 * j + cl;
                    int b = m >> 12, tt = m & 4095;
                    int h = n >> 6, d = n & 63;
                    Vt[((size_t)(b * NH + h) * DH + d) * LK + tt] = f2bf(acc[i][j][r]);
                }
    }
}

// ---------------- Q projection (small: 4.3 GF) on the 128^2 structure ----------------
__global__ __launch_bounds__(256, 2) void proj_q(const unsigned short* __restrict__ qb,
                                                 const unsigned short* __restrict__ W,
                                                 unsigned short* __restrict__ Qp) {
    __shared__ alignas(16) unsigned short As[2 * 128 * 64];
    __shared__ alignas(16) unsigned short Bs[2 * 128 * 64];
    const int x = blockIdx.x;            // 128 blocks: 16 mt x 8 nt
    const int mt = x & 15, nt = x >> 4;
    const unsigned short* A = qb;
    const unsigned short* Bw = W;        // Wq
    const int m0 = mt * 128, n0 = nt * 128;

    GEMM_DECLS
    GEMM_PIPELINE

    const int cl = lane & 15;
    const float QSCALE = 0.18033688011112042f;  // 0.125 * log2(e)
    for (int i = 0; i < 4; ++i)
        for (int j = 0; j < 4; ++j)
            for (int r = 0; r < 4; ++r) {
                int m = m0 + wr + 16 * i + g * 4 + r;
                int n = n0 + wc + 16 * j + cl;
                Qp[(size_t)m * 1024 + n] = f2bf(acc[i][j][r] * QSCALE);
            }
}

// ---------------- output projection (bf16 A, fp32 out) ----------------
__global__ __launch_bounds__(256, 2) void gemm_o(const unsigned short* __restrict__ A,
                                                 const unsigned short* __restrict__ Bw,
                                                 float* __restrict__ C) {
    __shared__ alignas(16) unsigned short As[2 * 128 * 64];
    __shared__ alignas(16) unsigned short Bs[2 * 128 * 64];
    const int m0 = blockIdx.x * 128, n0 = blockIdx.y * 128;

    GEMM_DECLS
    GEMM_PIPELINE

    const int cl = lane & 15;
    for (int i = 0; i < 4; ++i)
        for (int j = 0; j < 4; ++j)
            for (int r = 0; r < 4; ++r) {
                int m = m0 + wr + 16 * i + g * 4 + r;
                int n = n0 + wc + 16 * j + cl;
                C[(size_t)m * 1024 + n] = acc[i][j][r];
            }
}

// ---------------- flash attention, split-K=4, 32 q/wave, dbuf pipeline ----------------
// grid (256, 4): x = group (h=x&15, b=(x>>4)>>2, ck=(x>>4)&3), y = qt (128-q tiles).
// Per wave per issue: 4 gld16 -> steady outstanding 8 -> PIPE_BAR(4).
__global__ __launch_bounds__(256, 4) void attn(const unsigned short* __restrict__ Qp,
                                               const unsigned short* __restrict__ Kp,
                                               const unsigned short* __restrict__ Vt,
                                               float* __restrict__ OP, float* __restrict__ Lp) {
    __shared__ alignas(16) unsigned short Ks[2 * 64 * 64];
    __shared__ alignas(16) unsigned short Vs[2 * 64 * 64];
    const int tid = threadIdx.x, w = tid >> 6, lane = tid & 63;
    const int gid = blockIdx.x, qt = blockIdx.y;
    const int h = gid & 15, bck = gid >> 4;
    const int b = bck >> 2, ck = bck & 3;
    const int cl = lane & 15, g = lane >> 4;
    const int rx = cl & 7;

    // Q^T B-operand fragments for both q-groups (Q pre-scaled by 0.125*log2e)
    bf16x8 bq[2][2];
    for (int cg = 0; cg < 2; ++cg) {
        const size_t qrow = (size_t)(b * LQ + qt * 128 + w * 32 + cg * 16 + cl) * D_MODEL + h * DH;
        bq[cg][0] = *(const bf16x8*)(Qp + qrow + g * 8);
        bq[cg][1] = *(const bf16x8*)(Qp + qrow + 32 + g * 8);
    }

    float l_run[2] = {0.f, 0.f};
    f32x4 zero = {0.f, 0.f, 0.f, 0.f};
    f32x4 o[2][4];
    for (int cg = 0; cg < 2; ++cg)
        for (int i = 0; i < 4; ++i) o[cg][i] = zero;

    const int srow = lane >> 3;
    const int ssw = ((lane & 7) ^ srow) * 8;
    const int k0 = ck * (LK / 4);
    const unsigned short* kp = Kp + (size_t)b * LK * D_MODEL + h * DH +
                               (size_t)(k0 + w * 16 + srow) * D_MODEL + ssw;
    const unsigned short* vp = Vt + (size_t)(b * NH + h) * DH * LK +
                               (size_t)(w * 16 + srow) * LK + k0 + ssw;

#define ATTN_ISSUE(PAR) do {                                                   \
    unsigned short* kd = Ks + (PAR) * (64 * 64) + (w * 16) * 64;               \
    unsigned short* vd = Vs + (PAR) * (64 * 64) + (w * 16) * 64;               \
    gld16(kp, kd); gld16(kp + (size_t)8 * D_MODEL, kd + 8 * 64);               \
    gld16(vp, vd); gld16(vp + (size_t)8 * LK, vd + 8 * 64);                    \
    kp += (size_t)64 * D_MODEL; vp += 64;                                      \
} while (0)

#if HAVE_MFMA16
#define ATTN_PV(PAR) do {                                                      \
    for (int md = 0; md < 4; ++md) {                                           \
        const unsigned short* vr = Vs + (PAR) * (64 * 64) + (md * 16 + cl) * 64; \
        for (int ksv = 0; ksv < 4; ++ksv) {                                    \
            bf16x4 av = *(const bf16x4*)(vr + (((2 * ksv + (g >> 1)) ^ rx) << 3) + ((g & 1) << 2)); \
            for (int cg = 0; cg < 2; ++cg) {                                   \
                U4 pb; pb.u[0] = pk0[cg][ksv]; pb.u[1] = pk1[cg][ksv];         \
                o[cg][md] = MFMA16(av, pb.v, o[cg][md]);                       \
            }                                                                  \
        }                                                                      \
    }                                                                          \
} while (0)
#else
#define ATTN_PV(PAR) do {                                                      \
    for (int cg = 0; cg < 2; ++cg) {                                           \
        const int selA = ((((g & 1) << 5) | cl)) << 2;                         \
        const int selB = selA + 64;                                            \
        const int hi = g >> 1;                                                 \
        unsigned int ax0 = bperm(selA, pk0[cg][0]), ax1 = bperm(selA, pk0[cg][1]); \
        unsigned int ay0 = bperm(selA, pk1[cg][0]), ay1 = bperm(selA, pk1[cg][1]); \
        unsigned int bx0 = bperm(selB, pk0[cg][0]), bx1 = bperm(selB, pk0[cg][1]); \
        unsigned int by0 = bperm(selB, pk1[cg][0]), by1 = bperm(selB, pk1[cg][1]); \
        U8 b0;                                                                 \
        b0.u[0] = hi ? ax1 : ax0; b0.u[1] = hi ? ay1 : ay0;                    \
        b0.u[2] = hi ? bx1 : bx0; b0.u[3] = hi ? by1 : by0;                    \
        unsigned int cx0 = bperm(selA, pk0[cg][2]), cx1 = bperm(selA, pk0[cg][3]); \
        unsigned int cy0 = bperm(selA, pk1[cg][2]), cy1 = bperm(selA, pk1[cg][3]); \
        unsigned int dx0 = bperm(selB, pk0[cg][2]), dx1 = bperm(selB, pk0[cg][3]); \
        unsigned int dy0 = bperm(selB, pk1[cg][2]), dy1 = bperm(selB, pk1[cg][3]); \
        U8 b1;                                                                 \
        b1.u[0] = hi ? cx1 : cx0; b1.u[1] = hi ? cy1 : cy0;                    \
        b1.u[2] = hi ? dx1 : dx0; b1.u[3] = hi ? dy1 : dy0;                    \
        for (int md = 0; md < 4; ++md) {                                       \
            const unsigned short* vr = Vs + (PAR) * (64 * 64) + (md * 16 + cl) * 64; \
            bf16x8 av0 = *(const bf16x8*)(vr + ((g ^ rx) << 3));               \
            bf16x8 av1 = *(const bf16x8*)(vr + (((4 + g) ^ rx) << 3));         \
            o[cg][md] = MFMA32(av0, b0.v, o[cg][md]);                          \
            o[cg][md] = MFMA32(av1, b1.v, o[cg][md]);                          \
        }                                                                      \
    }                                                                          \
} while (0)
#endif

#define ATTN_COMPUTE(PAR) do {                                                 \
    unsigned int pk0[2][4], pk1[2][4];                                         \
    for (int mt = 0; mt < 4; ++mt) {                                           \
        const unsigned short* kr = Ks + (PAR) * (64 * 64) + (mt * 16 + cl) * 64; \
        bf16x8 a0 = *(const bf16x8*)(kr + ((g ^ rx) << 3));                    \
        bf16x8 a1 = *(const bf16x8*)(kr + (((4 + g) ^ rx) << 3));              \
        for (int cg = 0; cg < 2; ++cg) {                                       \
            f32x4 z = zero;                                                    \
            z = MFMA32(a0, bq[cg][0], z);                                      \
            z = MFMA32(a1, bq[cg][1], z);                                      \
            float p0 = EXP2F(z[0]), p1 = EXP2F(z[1]);                          \
            float p2 = EXP2F(z[2]), p3 = EXP2F(z[3]);                          \
            l_run[cg] += (p0 + p1) + (p2 + p3);                                \
            pk0[cg][mt] = packrn(p0, p1);                                      \
            pk1[cg][mt] = packrn(p2, p3);                                      \
        }                                                                      \
    }                                                                          \
    ATTN_PV(PAR);                                                              \
} while (0)

    ATTN_ISSUE(0); ATTN_ISSUE(1);
    for (int it = 0; it < 14; ++it) {
        PIPE_BAR(4);
        ATTN_COMPUTE(it & 1);
        END_BAR();
        ATTN_ISSUE(it & 1);
    }
    PIPE_BAR(4);
    ATTN_COMPUTE(0);
    PIPE_BAR(0);
    ATTN_COMPUTE(1);

    for (int cg = 0; cg < 2; ++cg) {
        float l = l_run[cg];
        l += __shfl_xor(l, 16);
        l += __shfl_xor(l, 32);
        const int q = qt * 128 + w * 32 + cg * 16 + cl;
        const size_t pidx = ((size_t)(b * NH + h) * LQ + q) * 4 + ck;
        for (int md = 0; md < 4; ++md)
            *(f32x4*)(OP + pidx * 64 + md * 16 + g * 4) = o[cg][md];
        if (g == 0) Lp[pidx] = l;
    }
}

// ---------------- split-K combine (plain sum; shared implicit max=0) ----------------
__global__ __launch_bounds__(256) void combine(const float* __restrict__ OP,
                                               const float* __restrict__ Lp,
                                               unsigned short* __restrict__ AO) {
    int t = blockIdx.x * 256 + threadIdx.x;      // 524288 threads
    int bhq = t >> 4, dg = (t & 15) * 4;
    float4 L4 = *(const float4*)(Lp + (size_t)bhq * 4);
    float inv = 1.f / (((L4.x + L4.y) + (L4.z + L4.w)));
    float4 acc = make_float4(0.f, 0.f, 0.f, 0.f);
    for (int c = 0; c < 4; ++c) {
        float4 v = *(const float4*)(OP + (size_t)(bhq * 4 + c) * 64 + dg);
        acc.x += v.x; acc.y += v.y; acc.z += v.z; acc.w += v.w;
    }
    int b = bhq >> 13, h = (bhq >> 9) & 15, q = bhq & 511;
    us4 ob;
    ob.x = f2bf(acc.x * inv); ob.y = f2bf(acc.y * inv);
    ob.z = f2bf(acc.z * inv); ob.w = f2bf(acc.w * inv);
    *(us4*)(AO + (size_t)(b * LQ + q) * D_MODEL + h * DH + dg) = ob;
}

// ---------------- launch ----------------
extern "C" void kernel_launch(void* const* d_in, const int* in_sizes, int n_in,
                              void* d_out, int out_size, void* d_ws, size_t ws_size,
                              hipStream_t stream) {
    const float* q_in = (const float*)d_in[0];
    const float* mem  = (const float*)d_in[1];
    const float* Wq = (const float*)d_in[3];
    const float* Wk = (const float*)d_in[4];
    const float* Wv = (const float*)d_in[5];
    const float* Wo = (const float*)d_in[6];
    float* out = (float*)d_out;

    constexpr size_t E_Q = (size_t)BB * LQ * D_MODEL;       // 2,097,152
    constexpr size_t E_M = (size_t)BB * LK * D_MODEL;       // 16,777,216
    constexpr size_t E_W = (size_t)D_MODEL * D_MODEL;       // 1,048,576
    constexpr size_t E_OP = (size_t)BB * NH * LQ * 4 * 64;  // 8,388,608 floats
    constexpr size_t E_L  = (size_t)BB * NH * LQ * 4;       // 131,072 floats

    float* OP = (float*)d_ws;
    float* Lp = OP + E_OP;
    unsigned short* qb   = (unsigned short*)(Lp + E_L);
    unsigned short* memb = qb + E_Q;
    unsigned short* wqb  = memb + E_M;          // Wq|Wk|Wv|Wo contiguous
    unsigned short* wob  = wqb + 3 * E_W;
    unsigned short* Qp   = wob + E_W;
    unsigned short* Kp   = Qp + E_Q;
    unsigned short* Vt   = Kp + E_M;
    unsigned short* AO   = Vt + E_M;

    constexpr int CVT_BLK = (int)((E_Q + E_M + 4 * E_W) / 4 / 256);  // 22528
    cvt_all<<<CVT_BLK, 256, 0, stream>>>(q_in, mem, Wq, Wk, Wv, Wo, qb);

    proj256<<<512, 512, 0, stream>>>(memb, wqb, Kp, Vt);
    proj_q<<<128, 256, 0, stream>>>(qb, wqb, Qp);

    attn<<<dim3(256, 4), 256, 0, stream>>>(Qp, Kp, Vt, OP, Lp);
    combine<<<2048, 256, 0, stream>>>(OP, Lp, AO);

    gemm_o<<<dim3(16, 8), 256, 0, stream>>>(AO, wob, out);
}

// Round 2
// 294.095 us; speedup vs baseline: 1.0348x; 1.0348x over previous
//
#include <hip/hip_runtime.h>

#define D_MODEL 1024
#define NH 16
#define DH 64
#define BB 4
#define LQ 512
#define LK 4096

typedef __attribute__((ext_vector_type(8))) short bf16x8;
typedef __attribute__((ext_vector_type(4))) short bf16x4;
typedef __attribute__((ext_vector_type(4))) float f32x4;
typedef __attribute__((ext_vector_type(4))) unsigned short us4;

union U4 { unsigned int u[2]; bf16x4 v; };
union U8 { unsigned int u[4]; bf16x8 v; };

#define MFMA32(a, b, c) __builtin_amdgcn_mfma_f32_16x16x32_bf16(a, b, c, 0, 0, 0)

#if __has_builtin(__builtin_amdgcn_mfma_f32_16x16x16bf16_1k)
#define HAVE_MFMA16 1
#define MFMA16(a, b, c) __builtin_amdgcn_mfma_f32_16x16x16bf16_1k(a, b, c, 0, 0, 0)
#else
#define HAVE_MFMA16 0
#endif

#if __has_builtin(__builtin_amdgcn_exp2f)
#define EXP2F __builtin_amdgcn_exp2f
#else
__device__ __forceinline__ float EXP2F(float x) { return __expf(x * 0.69314718056f); }
#endif

// Pipeline barriers for the 128^2 kernels (unchanged).
#define PIPE_BAR(KEEP) asm volatile("s_waitcnt vmcnt(" #KEEP ") lgkmcnt(0)\n\ts_barrier" ::: "memory")
#define END_BAR()      asm volatile("s_waitcnt lgkmcnt(0)\n\ts_barrier" ::: "memory")

__device__ __forceinline__ unsigned short f2bf(float f) {
    unsigned int u = __float_as_uint(f);
    u += 0x7fffu + ((u >> 16) & 1u);   // RNE
    return (unsigned short)(u >> 16);
}
__device__ __forceinline__ unsigned int packrn(float a, float b) {
    unsigned int ua = __float_as_uint(a) + 0x8000u;
    unsigned int ub = __float_as_uint(b) + 0x8000u;
    return __builtin_amdgcn_perm(ub, ua, 0x07060302u);
}
__device__ __forceinline__ void gld16(const void* g, void* l) {
    __builtin_amdgcn_global_load_lds(
        (__attribute__((address_space(1))) void*)(g),
        (__attribute__((address_space(3))) void*)(l), 16, 0, 0);
}
__device__ __forceinline__ unsigned int bperm(int srclane4, unsigned int v) {
    return (unsigned int)__builtin_amdgcn_ds_bpermute(srclane4, (int)v);
}

// ---------------- all fp32 -> bf16 converts, one launch ----------------
__global__ __launch_bounds__(256) void cvt_all(const float* __restrict__ q,
                                               const float* __restrict__ mem,
                                               const float* __restrict__ w0, const float* __restrict__ w1,
                                               const float* __restrict__ w2, const float* __restrict__ w3,
                                               unsigned short* __restrict__ dst) {
    constexpr size_t EQ = (size_t)BB * LQ * D_MODEL;
    constexpr size_t EM = (size_t)BB * LK * D_MODEL;
    constexpr size_t EW = (size_t)D_MODEL * D_MODEL;
    constexpr size_t R1 = EQ + EM;
    size_t i = ((size_t)blockIdx.x * 256 + threadIdx.x) * 4;
    const float* s; size_t o;
    if (i < EQ)                { s = q;   o = i; }
    else if (i < R1)           { s = mem; o = i - EQ; }
    else if (i < R1 + EW)      { s = w0;  o = i - R1; }
    else if (i < R1 + 2 * EW)  { s = w1;  o = i - R1 - EW; }
    else if (i < R1 + 3 * EW)  { s = w2;  o = i - R1 - 2 * EW; }
    else                       { s = w3;  o = i - R1 - 3 * EW; }
    float4 v = *(const float4*)(s + o);
    us4 ob;
    ob.x = f2bf(v.x); ob.y = f2bf(v.y); ob.z = f2bf(v.z); ob.w = f2bf(v.w);
    *(us4*)(dst + i) = ob;
}

// -------- shared GEMM-core macros: 128x128 tile, BK=64, 4 waves, dbuf pipeline --------
// (kept for proj_q + gemm_o)
#define GEMM_DECLS                                                                 \
    const int tid = threadIdx.x;                                                   \
    const int w = tid >> 6, lane = tid & 63;                                       \
    const int wr = (w >> 1) * 64, wc = (w & 1) * 64;                               \
    const int srow = lane >> 3, ssw = ((lane & 7) ^ srow) * 8;                     \
    const int fr = lane & 15, g = lane >> 4, frx = fr & 7;                         \
    f32x4 zero = {0.f, 0.f, 0.f, 0.f};                                             \
    f32x4 acc[4][4];                                                               \
    for (int i = 0; i < 4; ++i)                                                    \
        for (int j = 0; j < 4; ++j) acc[i][j] = zero;                              \
    const unsigned short* ga = A + (size_t)(m0 + w * 32 + srow) * 1024 + ssw;      \
    const unsigned short* gb = Bw + (size_t)(n0 + w * 32 + srow) * 1024 + ssw;

#define GEMM_ISSUE(PAR) do {                                                       \
    unsigned short* da = As + (PAR) * (128 * 64) + (w * 32) * 64;                  \
    unsigned short* db = Bs + (PAR) * (128 * 64) + (w * 32) * 64;                  \
    for (int c = 0; c < 4; ++c) {                                                  \
        gld16(ga + (size_t)c * 8 * 1024, da + c * 8 * 64);                         \
        gld16(gb + (size_t)c * 8 * 1024, db + c * 8 * 64);                         \
    }                                                                              \
    ga += 64; gb += 64;                                                            \
} while (0)

#define GEMM_COMPUTE(PAR) do {                                                     \
    const unsigned short* Ap = As + (PAR) * (128 * 64);                            \
    const unsigned short* Bp = Bs + (PAR) * (128 * 64);                            \
    for (int ks = 0; ks < 2; ++ks) {                                               \
        const int fx = ((ks * 4 + g) ^ frx) * 8;                                   \
        bf16x8 af[4], bfr[4];                                                      \
        for (int i = 0; i < 4; ++i) af[i] = *(const bf16x8*)(Ap + (wr + 16 * i + fr) * 64 + fx); \
        for (int j = 0; j < 4; ++j) bfr[j] = *(const bf16x8*)(Bp + (wc + 16 * j + fr) * 64 + fx); \
        for (int i = 0; i < 4; ++i)                                                \
            for (int j = 0; j < 4; ++j)                                            \
                acc[i][j] = MFMA32(af[i], bfr[j], acc[i][j]);                      \
    }                                                                              \
} while (0)

#define GEMM_PIPELINE                                                              \
    GEMM_ISSUE(0); GEMM_ISSUE(1);                                                  \
    for (int it = 0; it < 14; ++it) {                                              \
        PIPE_BAR(8);                                                               \
        GEMM_COMPUTE(it & 1);                                                      \
        END_BAR();                                                                 \
        GEMM_ISSUE(it & 1);                                                        \
    }                                                                              \
    PIPE_BAR(8);                                                                   \
    GEMM_COMPUTE(0);                                                               \
    PIPE_BAR(0);                                                                   \
    GEMM_COMPUTE(1);

// ================== 256x256-tile software-pipelined GEMM (K/V projections) ==================
// r1 post-mortem: reads-before-barrier + MFMA-after-barrier SERIALIZED LDS reads (~576 cyc)
// against MFMA (~620 cyc) -> MfmaUtil 28%. Fix: register double-buffer of fragments.
// Phase p: {ds_read frag[next]  (overlaps this phase's MFMA);
//           issue one 16KB gld16 piece; [vmcnt(4)@p1 / vmcnt(6)@p3];
//           setprio(1); 16 MFMA on frag[cur]; setprio(0);
//           lgkmcnt(0); s_barrier}                    -- ONE barrier per phase.
// 4-slot ring of [256 rows][32 K] per operand (128 KiB LDS). Wait/publish chains:
//   kh1(t)   staged t-1.p1/p2, drained by vmcnt(4)@t.p1, published b(t.p1), read t.p2  OK
//   kh0(t+1) staged t-1.p3/p4, drained by vmcnt(6)@t.p3, published b(t.p3), read t.p4  OK
//   every slot overwrite is >=2 end-barriers (each with lgkmcnt(0)) after its last read OK
#define SLOT_SH 8192  /* shorts per slot: 256*32 */

#define STAGE2(GB, LB, S, H) do {                                                  \
    const unsigned short* gs_ = (GB) + (size_t)(H) * 32;                           \
    unsigned short* ld_ = (LB) + (S) * SLOT_SH + tid * 8;                          \
    gld16(gs_, ld_);                                                               \
    gld16(gs_ + (size_t)131072, ld_ + 4096);  /* +128 rows / second half */        \
} while (0)

#define RD_A(DST, SLOT, I0_) do {                                                  \
    const unsigned short* Ap_ = As + (size_t)(SLOT) * SLOT_SH + aoff;              \
    DST[0] = *(const bf16x8*)(Ap_ + ((I0_) + 0) * 512);                            \
    DST[1] = *(const bf16x8*)(Ap_ + ((I0_) + 1) * 512);                            \
    DST[2] = *(const bf16x8*)(Ap_ + ((I0_) + 2) * 512);                            \
    DST[3] = *(const bf16x8*)(Ap_ + ((I0_) + 3) * 512);                            \
} while (0)

#define RD_B(DST, SLOT) do {                                                       \
    const unsigned short* Bp_ = Bs + (size_t)(SLOT) * SLOT_SH + boff;              \
    DST[0] = *(const bf16x8*)(Bp_ + 0 * 512);                                      \
    DST[1] = *(const bf16x8*)(Bp_ + 1 * 512);                                      \
    DST[2] = *(const bf16x8*)(Bp_ + 2 * 512);                                      \
    DST[3] = *(const bf16x8*)(Bp_ + 3 * 512);                                      \
} while (0)

#define MM(AF, BF, I0_) do {                                                       \
    __builtin_amdgcn_s_setprio(1);                                                 \
    _Pragma("unroll")                                                              \
    for (int ii = 0; ii < 4; ++ii) {                                               \
        _Pragma("unroll")                                                          \
        for (int jj = 0; jj < 4; ++jj)                                             \
            acc[(I0_) + ii][jj] = MFMA32(AF[ii], BF[jj], acc[(I0_) + ii][jj]);     \
    }                                                                              \
    __builtin_amdgcn_s_setprio(0);                                                 \
} while (0)

#define VW(N)  asm volatile("s_waitcnt vmcnt(" #N ")" ::: "memory")
#define PEND() asm volatile("s_waitcnt lgkmcnt(0)\n\ts_barrier" ::: "memory")

// One 64-K tile, steady state. Slots: S0=kh0(t), S1=kh1(t), Z1=kh1(t+1) dest,
// SN=kh0(t+1) src (read at p4); kh0(t+2) dest == S0 (4-slot ring, period 2 tiles).
#define PTILE(S0, S1, Z1, SN, H1, H0) do {                                         \
    RD_A(afB, (S0), 4); STAGE2(gA, As, (Z1), (H1)); VW(4); MM(afA, bfA, 0); PEND();\
    RD_A(afA, (S1), 0); RD_B(bfB, (S1)); STAGE2(gB, Bs, (Z1), (H1));               \
                                                    MM(afB, bfA, 4); PEND();       \
    RD_A(afB, (S1), 4); STAGE2(gA, As, (S0), (H0)); VW(6); MM(afA, bfB, 0); PEND();\
    RD_A(afA, (SN), 0); RD_B(bfA, (SN)); STAGE2(gB, Bs, (S0), (H0));               \
                                                    MM(afB, bfB, 4); PEND();       \
} while (0)

__global__ __launch_bounds__(512, 2) void proj256(const unsigned short* __restrict__ memb,
                                                  const unsigned short* __restrict__ W,  // wqb base: Wq|Wk|Wv|Wo
                                                  unsigned short* __restrict__ Kp,
                                                  unsigned short* __restrict__ Vt) {
    __shared__ alignas(16) unsigned short As[4 * SLOT_SH];   // 64 KiB
    __shared__ alignas(16) unsigned short Bs[4 * SLOT_SH];   // 64 KiB
    const int x = blockIdx.x;                     // 512 blocks = exactly 2 rounds of 256 CUs
    const int wg = ((x & 7) << 6) | (x >> 3);     // bijective XCD chunking: 64 wg/XCD
    const int isV = wg >> 8;                      // [0,256): K-proj, [256,512): V-proj
    const int mt = wg & 63, nt = (wg >> 6) & 3;
    const int m0 = mt * 256, n0 = nt * 256;
    const unsigned short* Bw = W + ((size_t)(1 + isV) << 20);  // Wk / Wv

    const int tid = threadIdx.x;
    const int lane = tid & 63, wid = tid >> 6;
    const int wm = wid >> 2, wn = wid & 3;
    const int fr = lane & 15, g = lane >> 4;
    const int sfr = (fr >> 1) & 3;                                   // swizzle bits for frag rows
    const int aoff = (wm * 128 + fr) * 32 + ((g ^ sfr) << 3);        // shorts into an A slot
    const int boff = (wn * 64 + fr) * 32 + ((g ^ sfr) << 3);         // shorts into a B slot

    f32x4 zero = {0.f, 0.f, 0.f, 0.f};
    f32x4 acc[8][4];
#pragma unroll
    for (int i = 0; i < 8; ++i)
#pragma unroll
        for (int j = 0; j < 4; ++j) acc[i][j] = zero;

    // staging addressing: thread covers rows (tid>>2) and (tid>>2)+128 of a piece,
    // 8-elem chunk (tid&3), with the inverse swizzle applied on the GLOBAL side.
    const int srow = tid >> 2;
    const int scg = (tid & 3) ^ ((tid >> 3) & 3);
    const unsigned short* gA = memb + (size_t)(m0 + srow) * 1024 + scg * 8;
    const unsigned short* gB = Bw + (size_t)(n0 + srow) * 1024 + scg * 8;

    // prologue: stage h=0,1,2 (slots 0,1,2); publish slot0; preload its fragments.
    STAGE2(gA, As, 0, 0); STAGE2(gB, Bs, 0, 0);
    STAGE2(gA, As, 1, 1); STAGE2(gB, Bs, 1, 1);
    STAGE2(gA, As, 2, 2); STAGE2(gB, Bs, 2, 2);
    VW(8);                                        // drain h0 (keep h1,h2 in flight)
    asm volatile("s_barrier" ::: "memory");
    bf16x8 afA[4], afB[4], bfA[4], bfB[4];
    RD_A(afA, 0, 0); RD_B(bfA, 0);                // compiler inserts lgkm before first MFMA

    for (int tt = 0; tt < 7; ++tt) {              // tiles t=0..13 (h up to 30)
        PTILE(0, 1, 3, 2, 4 * tt + 3, 4 * tt + 4);
        PTILE(2, 3, 1, 0, 4 * tt + 5, 4 * tt + 6);
    }
    // t = 14 (s0=0,s1=1,z1=3,sn=2): stage only h31 at p1/p2; peeled waits.
    RD_A(afB, 0, 4); STAGE2(gA, As, 3, 31); VW(4); MM(afA, bfA, 0); PEND();
    RD_A(afA, 1, 0); RD_B(bfB, 1); STAGE2(gB, Bs, 3, 31); MM(afB, bfA, 4); PEND();
    RD_A(afB, 1, 4); VW(4); MM(afA, bfB, 0); PEND();       // drains B-kh0(15)
    RD_A(afA, 2, 0); RD_B(bfA, 2); MM(afB, bfB, 4); PEND();
    // t = 15 (s0=2,s1=3): no staging; final vmcnt drain at p1.
    RD_A(afB, 2, 4); VW(0); MM(afA, bfA, 0); PEND();
    RD_A(afA, 3, 0); RD_B(bfB, 3); MM(afB, bfA, 4); PEND();
    RD_A(afB, 3, 4); MM(afA, bfB, 0); PEND();
    MM(afB, bfB, 4);

    // epilogue (same verified C/D mapping)
    const int cl = fr;
    if (!isV) {
#pragma unroll
        for (int i = 0; i < 8; ++i)
#pragma unroll
            for (int j = 0; j < 4; ++j)
#pragma unroll
                for (int r = 0; r < 4; ++r) {
                    int m = m0 + wm * 128 + 16 * i + g * 4 + r;
                    int n = n0 + wn * 64 + 16 * j + cl;
                    Kp[(size_t)m * 1024 + n] = f2bf(acc[i][j][r]);
                }
    } else {
#pragma unroll
        for (int i = 0; i < 8; ++i)
#pragma unroll
            for (int j = 0; j < 4; ++j)
#pragma unroll
                for (int r = 0; r < 4; ++r) {
                    int m = m0 + wm * 128 + 16 * i + g * 4 + r;
                    int n = n0 + wn * 64 + 16 * j + cl;
                    int b = m >> 12, tt2 = m & 4095;
                    int h = n >> 6, d = n & 63;
                    Vt[((size_t)(b * NH + h) * DH + d) * LK + tt2] = f2bf(acc[i][j][r]);
                }
    }
}

// ---------------- Q projection (small: 4.3 GF) on the 128^2 structure ----------------
__global__ __launch_bounds__(256, 2) void proj_q(const unsigned short* __restrict__ qb,
                                                 const unsigned short* __restrict__ W,
                                                 unsigned short* __restrict__ Qp) {
    __shared__ alignas(16) unsigned short As[2 * 128 * 64];
    __shared__ alignas(16) unsigned short Bs[2 * 128 * 64];
    const int x = blockIdx.x;            // 128 blocks: 16 mt x 8 nt
    const int mt = x & 15, nt = x >> 4;
    const unsigned short* A = qb;
    const unsigned short* Bw = W;        // Wq
    const int m0 = mt * 128, n0 = nt * 128;

    GEMM_DECLS
    GEMM_PIPELINE

    const int cl = lane & 15;
    const float QSCALE = 0.18033688011112042f;  // 0.125 * log2(e)
    for (int i = 0; i < 4; ++i)
        for (int j = 0; j < 4; ++j)
            for (int r = 0; r < 4; ++r) {
                int m = m0 + wr + 16 * i + g * 4 + r;
                int n = n0 + wc + 16 * j + cl;
                Qp[(size_t)m * 1024 + n] = f2bf(acc[i][j][r] * QSCALE);
            }
}

// ---------------- output projection (bf16 A, fp32 out) ----------------
__global__ __launch_bounds__(256, 2) void gemm_o(const unsigned short* __restrict__ A,
                                                 const unsigned short* __restrict__ Bw,
                                                 float* __restrict__ C) {
    __shared__ alignas(16) unsigned short As[2 * 128 * 64];
    __shared__ alignas(16) unsigned short Bs[2 * 128 * 64];
    const int m0 = blockIdx.x * 128, n0 = blockIdx.y * 128;

    GEMM_DECLS
    GEMM_PIPELINE

    const int cl = lane & 15;
    for (int i = 0; i < 4; ++i)
        for (int j = 0; j < 4; ++j)
            for (int r = 0; r < 4; ++r) {
                int m = m0 + wr + 16 * i + g * 4 + r;
                int n = n0 + wc + 16 * j + cl;
                C[(size_t)m * 1024 + n] = acc[i][j][r];
            }
}

// ---------------- flash attention, split-K=4, 32 q/wave, dbuf pipeline ----------------
__global__ __launch_bounds__(256, 4) void attn(const unsigned short* __restrict__ Qp,
                                               const unsigned short* __restrict__ Kp,
                                               const unsigned short* __restrict__ Vt,
                                               float* __restrict__ OP, float* __restrict__ Lp) {
    __shared__ alignas(16) unsigned short Ks[2 * 64 * 64];
    __shared__ alignas(16) unsigned short Vs[2 * 64 * 64];
    const int tid = threadIdx.x, w = tid >> 6, lane = tid & 63;
    const int gid = blockIdx.x, qt = blockIdx.y;
    const int h = gid & 15, bck = gid >> 4;
    const int b = bck >> 2, ck = bck & 3;
    const int cl = lane & 15, g = lane >> 4;
    const int rx = cl & 7;

    // Q^T B-operand fragments for both q-groups (Q pre-scaled by 0.125*log2e)
    bf16x8 bq[2][2];
    for (int cg = 0; cg < 2; ++cg) {
        const size_t qrow = (size_t)(b * LQ + qt * 128 + w * 32 + cg * 16 + cl) * D_MODEL + h * DH;
        bq[cg][0] = *(const bf16x8*)(Qp + qrow + g * 8);
        bq[cg][1] = *(const bf16x8*)(Qp + qrow + 32 + g * 8);
    }

    float l_run[2] = {0.f, 0.f};
    f32x4 zero = {0.f, 0.f, 0.f, 0.f};
    f32x4 o[2][4];
    for (int cg = 0; cg < 2; ++cg)
        for (int i = 0; i < 4; ++i) o[cg][i] = zero;

    const int srow = lane >> 3;
    const int ssw = ((lane & 7) ^ srow) * 8;
    const int k0 = ck * (LK / 4);
    const unsigned short* kp = Kp + (size_t)b * LK * D_MODEL + h * DH +
                               (size_t)(k0 + w * 16 + srow) * D_MODEL + ssw;
    const unsigned short* vp = Vt + (size_t)(b * NH + h) * DH * LK +
                               (size_t)(w * 16 + srow) * LK + k0 + ssw;

#define ATTN_ISSUE(PAR) do {                                                   \
    unsigned short* kd = Ks + (PAR) * (64 * 64) + (w * 16) * 64;               \
    unsigned short* vd = Vs + (PAR) * (64 * 64) + (w * 16) * 64;               \
    gld16(kp, kd); gld16(kp + (size_t)8 * D_MODEL, kd + 8 * 64);               \
    gld16(vp, vd); gld16(vp + (size_t)8 * LK, vd + 8 * 64);                    \
    kp += (size_t)64 * D_MODEL; vp += 64;                                      \
} while (0)

#if HAVE_MFMA16
#define ATTN_PV(PAR) do {                                                      \
    for (int md = 0; md < 4; ++md) {                                           \
        const unsigned short* vr = Vs + (PAR) * (64 * 64) + (md * 16 + cl) * 64; \
        for (int ksv = 0; ksv < 4; ++ksv) {                                    \
            bf16x4 av = *(const bf16x4*)(vr + (((2 * ksv + (g >> 1)) ^ rx) << 3) + ((g & 1) << 2)); \
            for (int cg = 0; cg < 2; ++cg) {                                   \
                U4 pb; pb.u[0] = pk0[cg][ksv]; pb.u[1] = pk1[cg][ksv];         \
                o[cg][md] = MFMA16(av, pb.v, o[cg][md]);                       \
            }                                                                  \
        }                                                                      \
    }                                                                          \
} while (0)
#else
#define ATTN_PV(PAR) do {                                                      \
    for (int cg = 0; cg < 2; ++cg) {                                           \
        const int selA = ((((g & 1) << 5) | cl)) << 2;                         \
        const int selB = selA + 64;                                            \
        const int hi = g >> 1;                                                 \
        unsigned int ax0 = bperm(selA, pk0[cg][0]), ax1 = bperm(selA, pk0[cg][1]); \
        unsigned int ay0 = bperm(selA, pk1[cg][0]), ay1 = bperm(selA, pk1[cg][1]); \
        unsigned int bx0 = bperm(selB, pk0[cg][0]), bx1 = bperm(selB, pk0[cg][1]); \
        unsigned int by0 = bperm(selB, pk1[cg][0]), by1 = bperm(selB, pk1[cg][1]); \
        U8 b0;                                                                 \
        b0.u[0] = hi ? ax1 : ax0; b0.u[1] = hi ? ay1 : ay0;                    \
        b0.u[2] = hi ? bx1 : bx0; b0.u[3] = hi ? by1 : by0;                    \
        unsigned int cx0 = bperm(selA, pk0[cg][2]), cx1 = bperm(selA, pk0[cg][3]); \
        unsigned int cy0 = bperm(selA, pk1[cg][2]), cy1 = bperm(selA, pk1[cg][3]); \
        unsigned int dx0 = bperm(selB, pk0[cg][2]), dx1 = bperm(selB, pk0[cg][3]); \
        unsigned int dy0 = bperm(selB, pk1[cg][2]), dy1 = bperm(selB, pk1[cg][3]); \
        U8 b1;                                                                 \
        b1.u[0] = hi ? cx1 : cx0; b1.u[1] = hi ? cy1 : cy0;                    \
        b1.u[2] = hi ? dx1 : dx0; b1.u[3] = hi ? dy1 : dy0;                    \
        for (int md = 0; md < 4; ++md) {                                       \
            const unsigned short* vr = Vs + (PAR) * (64 * 64) + (md * 16 + cl) * 64; \
            bf16x8 av0 = *(const bf16x8*)(vr + ((g ^ rx) << 3));               \
            bf16x8 av1 = *(const bf16x8*)(vr + (((4 + g) ^ rx) << 3));         \
            o[cg][md] = MFMA32(av0, b0.v, o[cg][md]);                          \
            o[cg][md] = MFMA32(av1, b1.v, o[cg][md]);                          \
        }                                                                      \
    }                                                                          \
} while (0)
#endif

#define ATTN_COMPUTE(PAR) do {                                                 \
    unsigned int pk0[2][4], pk1[2][4];                                         \
    for (int mt = 0; mt < 4; ++mt) {                                           \
        const unsigned short* kr = Ks + (PAR) * (64 * 64) + (mt * 16 + cl) * 64; \
        bf16x8 a0 = *(const bf16x8*)(kr + ((g ^ rx) << 3));                    \
        bf16x8 a1 = *(const bf16x8*)(kr + (((4 + g) ^ rx) << 3));              \
        for (int cg = 0; cg < 2; ++cg) {                                       \
            f32x4 z = zero;                                                    \
            z = MFMA32(a0, bq[cg][0], z);                                      \
            z = MFMA32(a1, bq[cg][1], z);                                      \
            float p0 = EXP2F(z[0]), p1 = EXP2F(z[1]);                          \
            float p2 = EXP2F(z[2]), p3 = EXP2F(z[3]);                          \
            l_run[cg] += (p0 + p1) + (p2 + p3);                                \
            pk0[cg][mt] = packrn(p0, p1);                                      \
            pk1[cg][mt] = packrn(p2, p3);                                      \
        }                                                                      \
    }                                                                          \
    ATTN_PV(PAR);                                                              \
} while (0)

    ATTN_ISSUE(0); ATTN_ISSUE(1);
    for (int it = 0; it < 14; ++it) {
        PIPE_BAR(4);
        ATTN_COMPUTE(it & 1);
        END_BAR();
        ATTN_ISSUE(it & 1);
    }
    PIPE_BAR(4);
    ATTN_COMPUTE(0);
    PIPE_BAR(0);
    ATTN_COMPUTE(1);

    for (int cg = 0; cg < 2; ++cg) {
        float l = l_run[cg];
        l += __shfl_xor(l, 16);
        l += __shfl_xor(l, 32);
        const int q = qt * 128 + w * 32 + cg * 16 + cl;
        const size_t pidx = ((size_t)(b * NH + h) * LQ + q) * 4 + ck;
        for (int md = 0; md < 4; ++md)
            *(f32x4*)(OP + pidx * 64 + md * 16 + g * 4) = o[cg][md];
        if (g == 0) Lp[pidx] = l;
    }
}

// ---------------- split-K combine (plain sum; shared implicit max=0) ----------------
__global__ __launch_bounds__(256) void combine(const float* __restrict__ OP,
                                               const float* __restrict__ Lp,
                                               unsigned short* __restrict__ AO) {
    int t = blockIdx.x * 256 + threadIdx.x;      // 524288 threads
    int bhq = t >> 4, dg = (t & 15) * 4;
    float4 L4 = *(const float4*)(Lp + (size_t)bhq * 4);
    float inv = 1.f / (((L4.x + L4.y) + (L4.z + L4.w)));
    float4 acc = make_float4(0.f, 0.f, 0.f, 0.f);
    for (int c = 0; c < 4; ++c) {
        float4 v = *(const float4*)(OP + (size_t)(bhq * 4 + c) * 64 + dg);
        acc.x += v.x; acc.y += v.y; acc.z += v.z; acc.w += v.w;
    }
    int b = bhq >> 13, h = (bhq >> 9) & 15, q = bhq & 511;
    us4 ob;
    ob.x = f2bf(acc.x * inv); ob.y = f2bf(acc.y * inv);
    ob.z = f2bf(acc.z * inv); ob.w = f2bf(acc.w * inv);
    *(us4*)(AO + (size_t)(b * LQ + q) * D_MODEL + h * DH + dg) = ob;
}

// ---------------- launch ----------------
extern "C" void kernel_launch(void* const* d_in, const int* in_sizes, int n_in,
                              void* d_out, int out_size, void* d_ws, size_t ws_size,
                              hipStream_t stream) {
    const float* q_in = (const float*)d_in[0];
    const float* mem  = (const float*)d_in[1];
    const float* Wq = (const float*)d_in[3];
    const float* Wk = (const float*)d_in[4];
    const float* Wv = (const float*)d_in[5];
    const float* Wo = (const float*)d_in[6];
    float* out = (float*)d_out;

    constexpr size_t E_Q = (size_t)BB * LQ * D_MODEL;       // 2,097,152
    constexpr size_t E_M = (size_t)BB * LK * D_MODEL;       // 16,777,216
    constexpr size_t E_W = (size_t)D_MODEL * D_MODEL;       // 1,048,576
    constexpr size_t E_OP = (size_t)BB * NH * LQ * 4 * 64;  // 8,388,608 floats
    constexpr size_t E_L  = (size_t)BB * NH * LQ * 4;       // 131,072 floats

    float* OP = (float*)d_ws;
    float* Lp = OP + E_OP;
    unsigned short* qb   = (unsigned short*)(Lp + E_L);
    unsigned short* memb = qb + E_Q;
    unsigned short* wqb  = memb + E_M;          // Wq|Wk|Wv|Wo contiguous
    unsigned short* wob  = wqb + 3 * E_W;
    unsigned short* Qp   = wob + E_W;
    unsigned short* Kp   = Qp + E_Q;
    unsigned short* Vt   = Kp + E_M;
    unsigned short* AO   = Vt + E_M;

    constexpr int CVT_BLK = (int)((E_Q + E_M + 4 * E_W) / 4 / 256);  // 22528
    cvt_all<<<CVT_BLK, 256, 0, stream>>>(q_in, mem, Wq, Wk, Wv, Wo, qb);

    proj256<<<512, 512, 0, stream>>>(memb, wqb, Kp, Vt);
    proj_q<<<128, 256, 0, stream>>>(qb, wqb, Qp);

    attn<<<dim3(256, 4), 256, 0, stream>>>(Qp, Kp, Vt, OP, Lp);
    combine<<<2048, 256, 0, stream>>>(OP, Lp, AO);

    gemm_o<<<dim3(16, 8), 256, 0, stream>>>(AO, wob, out);
}

// Round 3
// 290.601 us; speedup vs baseline: 1.0473x; 1.0120x over previous
//
#include <hip/hip_runtime.h>

#define D_MODEL 1024
#define NH 16
#define DH 64
#define BB 4
#define LQ 512
#define LK 4096

typedef __attribute__((ext_vector_type(8))) short bf16x8;
typedef __attribute__((ext_vector_type(4))) short bf16x4;
typedef __attribute__((ext_vector_type(4))) float f32x4;
typedef __attribute__((ext_vector_type(4))) unsigned short us4;

union U4 { unsigned int u[2]; bf16x4 v; };
union U8 { unsigned int u[4]; bf16x8 v; };

#define MFMA32(a, b, c) __builtin_amdgcn_mfma_f32_16x16x32_bf16(a, b, c, 0, 0, 0)

#if __has_builtin(__builtin_amdgcn_mfma_f32_16x16x16bf16_1k)
#define HAVE_MFMA16 1
#define MFMA16(a, b, c) __builtin_amdgcn_mfma_f32_16x16x16bf16_1k(a, b, c, 0, 0, 0)
#else
#define HAVE_MFMA16 0
#endif

#if __has_builtin(__builtin_amdgcn_exp2f)
#define EXP2F __builtin_amdgcn_exp2f
#else
__device__ __forceinline__ float EXP2F(float x) { return __expf(x * 0.69314718056f); }
#endif

// Pipeline barriers for the 128^2 kernels (unchanged).
#define PIPE_BAR(KEEP) asm volatile("s_waitcnt vmcnt(" #KEEP ") lgkmcnt(0)\n\ts_barrier" ::: "memory")
#define END_BAR()      asm volatile("s_waitcnt lgkmcnt(0)\n\ts_barrier" ::: "memory")

__device__ __forceinline__ unsigned short f2bf(float f) {
    unsigned int u = __float_as_uint(f);
    u += 0x7fffu + ((u >> 16) & 1u);   // RNE
    return (unsigned short)(u >> 16);
}
__device__ __forceinline__ unsigned int packrn(float a, float b) {
    unsigned int ua = __float_as_uint(a) + 0x8000u;
    unsigned int ub = __float_as_uint(b) + 0x8000u;
    return __builtin_amdgcn_perm(ub, ua, 0x07060302u);
}
__device__ __forceinline__ void gld16(const void* g, void* l) {
    __builtin_amdgcn_global_load_lds(
        (__attribute__((address_space(1))) void*)(g),
        (__attribute__((address_space(3))) void*)(l), 16, 0, 0);
}
__device__ __forceinline__ unsigned int bperm(int srclane4, unsigned int v) {
    return (unsigned int)__builtin_amdgcn_ds_bpermute(srclane4, (int)v);
}

// ---------------- all fp32 -> bf16 converts, one launch ----------------
__global__ __launch_bounds__(256) void cvt_all(const float* __restrict__ q,
                                               const float* __restrict__ mem,
                                               const float* __restrict__ w0, const float* __restrict__ w1,
                                               const float* __restrict__ w2, const float* __restrict__ w3,
                                               unsigned short* __restrict__ dst) {
    constexpr size_t EQ = (size_t)BB * LQ * D_MODEL;
    constexpr size_t EM = (size_t)BB * LK * D_MODEL;
    constexpr size_t EW = (size_t)D_MODEL * D_MODEL;
    constexpr size_t R1 = EQ + EM;
    size_t i = ((size_t)blockIdx.x * 256 + threadIdx.x) * 4;
    const float* s; size_t o;
    if (i < EQ)                { s = q;   o = i; }
    else if (i < R1)           { s = mem; o = i - EQ; }
    else if (i < R1 + EW)      { s = w0;  o = i - R1; }
    else if (i < R1 + 2 * EW)  { s = w1;  o = i - R1 - EW; }
    else if (i < R1 + 3 * EW)  { s = w2;  o = i - R1 - 2 * EW; }
    else                       { s = w3;  o = i - R1 - 3 * EW; }
    float4 v = *(const float4*)(s + o);
    us4 ob;
    ob.x = f2bf(v.x); ob.y = f2bf(v.y); ob.z = f2bf(v.z); ob.w = f2bf(v.w);
    *(us4*)(dst + i) = ob;
}

// -------- shared GEMM-core macros: 128x128 tile, BK=64, 4 waves, dbuf pipeline --------
// (kept for proj_q + gemm_o)
#define GEMM_DECLS                                                                 \
    const int tid = threadIdx.x;                                                   \
    const int w = tid >> 6, lane = tid & 63;                                       \
    const int wr = (w >> 1) * 64, wc = (w & 1) * 64;                               \
    const int srow = lane >> 3, ssw = ((lane & 7) ^ srow) * 8;                     \
    const int fr = lane & 15, g = lane >> 4, frx = fr & 7;                         \
    f32x4 zero = {0.f, 0.f, 0.f, 0.f};                                             \
    f32x4 acc[4][4];                                                               \
    for (int i = 0; i < 4; ++i)                                                    \
        for (int j = 0; j < 4; ++j) acc[i][j] = zero;                              \
    const unsigned short* ga = A + (size_t)(m0 + w * 32 + srow) * 1024 + ssw;      \
    const unsigned short* gb = Bw + (size_t)(n0 + w * 32 + srow) * 1024 + ssw;

#define GEMM_ISSUE(PAR) do {                                                       \
    unsigned short* da = As + (PAR) * (128 * 64) + (w * 32) * 64;                  \
    unsigned short* db = Bs + (PAR) * (128 * 64) + (w * 32) * 64;                  \
    for (int c = 0; c < 4; ++c) {                                                  \
        gld16(ga + (size_t)c * 8 * 1024, da + c * 8 * 64);                         \
        gld16(gb + (size_t)c * 8 * 1024, db + c * 8 * 64);                         \
    }                                                                              \
    ga += 64; gb += 64;                                                            \
} while (0)

#define GEMM_COMPUTE(PAR) do {                                                     \
    const unsigned short* Ap = As + (PAR) * (128 * 64);                            \
    const unsigned short* Bp = Bs + (PAR) * (128 * 64);                            \
    for (int ks = 0; ks < 2; ++ks) {                                               \
        const int fx = ((ks * 4 + g) ^ frx) * 8;                                   \
        bf16x8 af[4], bfr[4];                                                      \
        for (int i = 0; i < 4; ++i) af[i] = *(const bf16x8*)(Ap + (wr + 16 * i + fr) * 64 + fx); \
        for (int j = 0; j < 4; ++j) bfr[j] = *(const bf16x8*)(Bp + (wc + 16 * j + fr) * 64 + fx); \
        for (int i = 0; i < 4; ++i)                                                \
            for (int j = 0; j < 4; ++j)                                            \
                acc[i][j] = MFMA32(af[i], bfr[j], acc[i][j]);                      \
    }                                                                              \
} while (0)

#define GEMM_PIPELINE                                                              \
    GEMM_ISSUE(0); GEMM_ISSUE(1);                                                  \
    for (int it = 0; it < 14; ++it) {                                              \
        PIPE_BAR(8);                                                               \
        GEMM_COMPUTE(it & 1);                                                      \
        END_BAR();                                                                 \
        GEMM_ISSUE(it & 1);                                                        \
    }                                                                              \
    PIPE_BAR(8);                                                                   \
    GEMM_COMPUTE(0);                                                               \
    PIPE_BAR(0);                                                                   \
    GEMM_COMPUTE(1);

// ================== 256x256-tile software-pipelined GEMM (K/V projections) ==================
// r3 change: block->tile mapping shares the A-tile within an XCD. Each XCD-round's 32
// blocks = 4 A-tiles x 8 strips (nt0..3 x {K,V}); the 8 blocks touching one A-tile run
// concurrently on one XCD -> A-loads MSHR-merge/L2-hit; A fetched from HBM ~once (32 MB
// instead of ~128 MB; r2 FETCH=136MB matched memb x4 and per-XCD ingest 344 GB/s matched
// the 1747 cyc/phase). Also: counted vmcnt waits moved AFTER the MFMA cluster.
#define SLOT_SH 8192  /* shorts per slot: 256*32 */

#define STAGE2(GB, LB, S, H) do {                                                  \
    const unsigned short* gs_ = (GB) + (size_t)(H) * 32;                           \
    unsigned short* ld_ = (LB) + (S) * SLOT_SH + tid * 8;                          \
    gld16(gs_, ld_);                                                               \
    gld16(gs_ + (size_t)131072, ld_ + 4096);  /* +128 rows / second half */        \
} while (0)

#define RD_A(DST, SLOT, I0_) do {                                                  \
    const unsigned short* Ap_ = As + (size_t)(SLOT) * SLOT_SH + aoff;              \
    DST[0] = *(const bf16x8*)(Ap_ + ((I0_) + 0) * 512);                            \
    DST[1] = *(const bf16x8*)(Ap_ + ((I0_) + 1) * 512);                            \
    DST[2] = *(const bf16x8*)(Ap_ + ((I0_) + 2) * 512);                            \
    DST[3] = *(const bf16x8*)(Ap_ + ((I0_) + 3) * 512);                            \
} while (0)

#define RD_B(DST, SLOT) do {                                                       \
    const unsigned short* Bp_ = Bs + (size_t)(SLOT) * SLOT_SH + boff;              \
    DST[0] = *(const bf16x8*)(Bp_ + 0 * 512);                                      \
    DST[1] = *(const bf16x8*)(Bp_ + 1 * 512);                                      \
    DST[2] = *(const bf16x8*)(Bp_ + 2 * 512);                                      \
    DST[3] = *(const bf16x8*)(Bp_ + 3 * 512);                                      \
} while (0)

#define MM(AF, BF, I0_) do {                                                       \
    __builtin_amdgcn_s_setprio(1);                                                 \
    _Pragma("unroll")                                                              \
    for (int ii = 0; ii < 4; ++ii) {                                               \
        _Pragma("unroll")                                                          \
        for (int jj = 0; jj < 4; ++jj)                                             \
            acc[(I0_) + ii][jj] = MFMA32(AF[ii], BF[jj], acc[(I0_) + ii][jj]);     \
    }                                                                              \
    __builtin_amdgcn_s_setprio(0);                                                 \
} while (0)

#define VW(N)  asm volatile("s_waitcnt vmcnt(" #N ")" ::: "memory")
#define PEND() asm volatile("s_waitcnt lgkmcnt(0)\n\ts_barrier" ::: "memory")

// One 64-K tile, steady state. Slots: S0=kh0(t), S1=kh1(t), Z1=kh1(t+1) dest,
// SN=kh0(t+1) src (read at p4); kh0(t+2) dest == S0 (4-slot ring, period 2 tiles).
// vmcnt drains sit AFTER the MFMA cluster (publish only needs to precede the barrier).
#define PTILE(S0, S1, Z1, SN, H1, H0) do {                                         \
    RD_A(afB, (S0), 4); STAGE2(gA, As, (Z1), (H1)); MM(afA, bfA, 0); VW(4); PEND();\
    RD_A(afA, (S1), 0); RD_B(bfB, (S1)); STAGE2(gB, Bs, (Z1), (H1));               \
                                                    MM(afB, bfA, 4); PEND();       \
    RD_A(afB, (S1), 4); STAGE2(gA, As, (S0), (H0)); MM(afA, bfB, 0); VW(6); PEND();\
    RD_A(afA, (SN), 0); RD_B(bfA, (SN)); STAGE2(gB, Bs, (S0), (H0));               \
                                                    MM(afB, bfB, 4); PEND();       \
} while (0)

__global__ __launch_bounds__(512, 2) void proj256(const unsigned short* __restrict__ memb,
                                                  const unsigned short* __restrict__ W,  // wqb base: Wq|Wk|Wv|Wo
                                                  unsigned short* __restrict__ Kp,
                                                  unsigned short* __restrict__ Vt) {
    __shared__ alignas(16) unsigned short As[4 * SLOT_SH];   // 64 KiB
    __shared__ alignas(16) unsigned short Bs[4 * SLOT_SH];   // 64 KiB
    // 512 blocks = 2 rounds of 256. Per XCD-round: 32 blocks = 4 A-tiles x 8 strips
    // (nt 0..3 x {K,V}) -> A-tile shared by 8 concurrent blocks on one XCD.
    const int x = blockIdx.x;
    const int xcd = x & 7, s = x >> 3;            // HW dispatch: block x -> XCD x%8
    const int rnd = s >> 5, i5 = s & 31;          // 2 rounds x 32 concurrent slots
    const int mt = xcd * 8 + rnd * 4 + (i5 >> 3); // 4 A-tiles per XCD-round (disjoint across XCDs)
    const int strip = i5 & 7;
    const int isV = strip >> 2, nt = strip & 3;
    const int m0 = mt * 256, n0 = nt * 256;
    const unsigned short* Bw = W + ((size_t)(1 + isV) << 20);  // Wk / Wv

    const int tid = threadIdx.x;
    const int lane = tid & 63, wid = tid >> 6;
    const int wm = wid >> 2, wn = wid & 3;
    const int fr = lane & 15, g = lane >> 4;
    const int sfr = (fr >> 1) & 3;                                   // swizzle bits for frag rows
    const int aoff = (wm * 128 + fr) * 32 + ((g ^ sfr) << 3);        // shorts into an A slot
    const int boff = (wn * 64 + fr) * 32 + ((g ^ sfr) << 3);         // shorts into a B slot

    f32x4 zero = {0.f, 0.f, 0.f, 0.f};
    f32x4 acc[8][4];
#pragma unroll
    for (int i = 0; i < 8; ++i)
#pragma unroll
        for (int j = 0; j < 4; ++j) acc[i][j] = zero;

    // staging addressing: thread covers rows (tid>>2) and (tid>>2)+128 of a piece,
    // 8-elem chunk (tid&3), with the inverse swizzle applied on the GLOBAL side.
    const int srow = tid >> 2;
    const int scg = (tid & 3) ^ ((tid >> 3) & 3);
    const unsigned short* gA = memb + (size_t)(m0 + srow) * 1024 + scg * 8;
    const unsigned short* gB = Bw + (size_t)(n0 + srow) * 1024 + scg * 8;

    // prologue: stage h=0,1,2 (slots 0,1,2); publish slot0; preload its fragments.
    STAGE2(gA, As, 0, 0); STAGE2(gB, Bs, 0, 0);
    STAGE2(gA, As, 1, 1); STAGE2(gB, Bs, 1, 1);
    STAGE2(gA, As, 2, 2); STAGE2(gB, Bs, 2, 2);
    VW(8);                                        // drain h0 (keep h1,h2 in flight)
    asm volatile("s_barrier" ::: "memory");
    bf16x8 afA[4], afB[4], bfA[4], bfB[4];
    RD_A(afA, 0, 0); RD_B(bfA, 0);                // compiler inserts lgkm before first MFMA

    for (int tt = 0; tt < 7; ++tt) {              // tiles t=0..13 (h up to 30)
        PTILE(0, 1, 3, 2, 4 * tt + 3, 4 * tt + 4);
        PTILE(2, 3, 1, 0, 4 * tt + 5, 4 * tt + 6);
    }
    // t = 14 (s0=0,s1=1,z1=3,sn=2): stage only h31 at p1/p2; peeled waits.
    RD_A(afB, 0, 4); STAGE2(gA, As, 3, 31); MM(afA, bfA, 0); VW(4); PEND();
    RD_A(afA, 1, 0); RD_B(bfB, 1); STAGE2(gB, Bs, 3, 31); MM(afB, bfA, 4); PEND();
    RD_A(afB, 1, 4); MM(afA, bfB, 0); VW(4); PEND();       // drains B-kh0(15)
    RD_A(afA, 2, 0); RD_B(bfA, 2); MM(afB, bfB, 4); PEND();
    // t = 15 (s0=2,s1=3): no staging; final vmcnt drain at p1.
    RD_A(afB, 2, 4); MM(afA, bfA, 0); VW(0); PEND();
    RD_A(afA, 3, 0); RD_B(bfB, 3); MM(afB, bfA, 4); PEND();
    RD_A(afB, 3, 4); MM(afA, bfB, 0); PEND();
    MM(afB, bfB, 4);

    // epilogue (same verified C/D mapping)
    const int cl = fr;
    if (!isV) {
#pragma unroll
        for (int i = 0; i < 8; ++i)
#pragma unroll
            for (int j = 0; j < 4; ++j)
#pragma unroll
                for (int r = 0; r < 4; ++r) {
                    int m = m0 + wm * 128 + 16 * i + g * 4 + r;
                    int n = n0 + wn * 64 + 16 * j + cl;
                    Kp[(size_t)m * 1024 + n] = f2bf(acc[i][j][r]);
                }
    } else {
#pragma unroll
        for (int i = 0; i < 8; ++i)
#pragma unroll
            for (int j = 0; j < 4; ++j)
#pragma unroll
                for (int r = 0; r < 4; ++r) {
                    int m = m0 + wm * 128 + 16 * i + g * 4 + r;
                    int n = n0 + wn * 64 + 16 * j + cl;
                    int b = m >> 12, tt2 = m & 4095;
                    int h = n >> 6, d = n & 63;
                    Vt[((size_t)(b * NH + h) * DH + d) * LK + tt2] = f2bf(acc[i][j][r]);
                }
    }
}

// ---------------- Q projection (small: 4.3 GF) on the 128^2 structure ----------------
__global__ __launch_bounds__(256, 2) void proj_q(const unsigned short* __restrict__ qb,
                                                 const unsigned short* __restrict__ W,
                                                 unsigned short* __restrict__ Qp) {
    __shared__ alignas(16) unsigned short As[2 * 128 * 64];
    __shared__ alignas(16) unsigned short Bs[2 * 128 * 64];
    const int x = blockIdx.x;            // 128 blocks: 16 mt x 8 nt
    const int mt = x & 15, nt = x >> 4;
    const unsigned short* A = qb;
    const unsigned short* Bw = W;        // Wq
    const int m0 = mt * 128, n0 = nt * 128;

    GEMM_DECLS
    GEMM_PIPELINE

    const int cl = lane & 15;
    const float QSCALE = 0.18033688011112042f;  // 0.125 * log2(e)
    for (int i = 0; i < 4; ++i)
        for (int j = 0; j < 4; ++j)
            for (int r = 0; r < 4; ++r) {
                int m = m0 + wr + 16 * i + g * 4 + r;
                int n = n0 + wc + 16 * j + cl;
                Qp[(size_t)m * 1024 + n] = f2bf(acc[i][j][r] * QSCALE);
            }
}

// ---------------- output projection (bf16 A, fp32 out) ----------------
__global__ __launch_bounds__(256, 2) void gemm_o(const unsigned short* __restrict__ A,
                                                 const unsigned short* __restrict__ Bw,
                                                 float* __restrict__ C) {
    __shared__ alignas(16) unsigned short As[2 * 128 * 64];
    __shared__ alignas(16) unsigned short Bs[2 * 128 * 64];
    const int m0 = blockIdx.x * 128, n0 = blockIdx.y * 128;

    GEMM_DECLS
    GEMM_PIPELINE

    const int cl = lane & 15;
    for (int i = 0; i < 4; ++i)
        for (int j = 0; j < 4; ++j)
            for (int r = 0; r < 4; ++r) {
                int m = m0 + wr + 16 * i + g * 4 + r;
                int n = n0 + wc + 16 * j + cl;
                C[(size_t)m * 1024 + n] = acc[i][j][r];
            }
}

// ---------------- flash attention, split-K=4, 32 q/wave, dbuf pipeline ----------------
__global__ __launch_bounds__(256, 4) void attn(const unsigned short* __restrict__ Qp,
                                               const unsigned short* __restrict__ Kp,
                                               const unsigned short* __restrict__ Vt,
                                               float* __restrict__ OP, float* __restrict__ Lp) {
    __shared__ alignas(16) unsigned short Ks[2 * 64 * 64];
    __shared__ alignas(16) unsigned short Vs[2 * 64 * 64];
    const int tid = threadIdx.x, w = tid >> 6, lane = tid & 63;
    const int gid = blockIdx.x, qt = blockIdx.y;
    const int h = gid & 15, bck = gid >> 4;
    const int b = bck >> 2, ck = bck & 3;
    const int cl = lane & 15, g = lane >> 4;
    const int rx = cl & 7;

    // Q^T B-operand fragments for both q-groups (Q pre-scaled by 0.125*log2e)
    bf16x8 bq[2][2];
    for (int cg = 0; cg < 2; ++cg) {
        const size_t qrow = (size_t)(b * LQ + qt * 128 + w * 32 + cg * 16 + cl) * D_MODEL + h * DH;
        bq[cg][0] = *(const bf16x8*)(Qp + qrow + g * 8);
        bq[cg][1] = *(const bf16x8*)(Qp + qrow + 32 + g * 8);
    }

    float l_run[2] = {0.f, 0.f};
    f32x4 zero = {0.f, 0.f, 0.f, 0.f};
    f32x4 o[2][4];
    for (int cg = 0; cg < 2; ++cg)
        for (int i = 0; i < 4; ++i) o[cg][i] = zero;

    const int srow = lane >> 3;
    const int ssw = ((lane & 7) ^ srow) * 8;
    const int k0 = ck * (LK / 4);
    const unsigned short* kp = Kp + (size_t)b * LK * D_MODEL + h * DH +
                               (size_t)(k0 + w * 16 + srow) * D_MODEL + ssw;
    const unsigned short* vp = Vt + (size_t)(b * NH + h) * DH * LK +
                               (size_t)(w * 16 + srow) * LK + k0 + ssw;

#define ATTN_ISSUE(PAR) do {                                                   \
    unsigned short* kd = Ks + (PAR) * (64 * 64) + (w * 16) * 64;               \
    unsigned short* vd = Vs + (PAR) * (64 * 64) + (w * 16) * 64;               \
    gld16(kp, kd); gld16(kp + (size_t)8 * D_MODEL, kd + 8 * 64);               \
    gld16(vp, vd); gld16(vp + (size_t)8 * LK, vd + 8 * 64);                    \
    kp += (size_t)64 * D_MODEL; vp += 64;                                      \
} while (0)

#if HAVE_MFMA16
#define ATTN_PV(PAR) do {                                                      \
    for (int md = 0; md < 4; ++md) {                                           \
        const unsigned short* vr = Vs + (PAR) * (64 * 64) + (md * 16 + cl) * 64; \
        for (int ksv = 0; ksv < 4; ++ksv) {                                    \
            bf16x4 av = *(const bf16x4*)(vr + (((2 * ksv + (g >> 1)) ^ rx) << 3) + ((g & 1) << 2)); \
            for (int cg = 0; cg < 2; ++cg) {                                   \
                U4 pb; pb.u[0] = pk0[cg][ksv]; pb.u[1] = pk1[cg][ksv];         \
                o[cg][md] = MFMA16(av, pb.v, o[cg][md]);                       \
            }                                                                  \
        }                                                                      \
    }                                                                          \
} while (0)
#else
#define ATTN_PV(PAR) do {                                                      \
    for (int cg = 0; cg < 2; ++cg) {                                           \
        const int selA = ((((g & 1) << 5) | cl)) << 2;                         \
        const int selB = selA + 64;                                            \
        const int hi = g >> 1;                                                 \
        unsigned int ax0 = bperm(selA, pk0[cg][0]), ax1 = bperm(selA, pk0[cg][1]); \
        unsigned int ay0 = bperm(selA, pk1[cg][0]), ay1 = bperm(selA, pk1[cg][1]); \
        unsigned int bx0 = bperm(selB, pk0[cg][0]), bx1 = bperm(selB, pk0[cg][1]); \
        unsigned int by0 = bperm(selB, pk1[cg][0]), by1 = bperm(selB, pk1[cg][1]); \
        U8 b0;                                                                 \
        b0.u[0] = hi ? ax1 : ax0; b0.u[1] = hi ? ay1 : ay0;                    \
        b0.u[2] = hi ? bx1 : bx0; b0.u[3] = hi ? by1 : by0;                    \
        unsigned int cx0 = bperm(selA, pk0[cg][2]), cx1 = bperm(selA, pk0[cg][3]); \
        unsigned int cy0 = bperm(selA, pk1[cg][2]), cy1 = bperm(selA, pk1[cg][3]); \
        unsigned int dx0 = bperm(selB, pk0[cg][2]), dx1 = bperm(selB, pk0[cg][3]); \
        unsigned int dy0 = bperm(selB, pk1[cg][2]), dy1 = bperm(selB, pk1[cg][3]); \
        U8 b1;                                                                 \
        b1.u[0] = hi ? cx1 : cx0; b1.u[1] = hi ? cy1 : cy0;                    \
        b1.u[2] = hi ? dx1 : dx0; b1.u[3] = hi ? dy1 : dy0;                    \
        for (int md = 0; md < 4; ++md) {                                       \
            const unsigned short* vr = Vs + (PAR) * (64 * 64) + (md * 16 + cl) * 64; \
            bf16x8 av0 = *(const bf16x8*)(vr + ((g ^ rx) << 3));               \
            bf16x8 av1 = *(const bf16x8*)(vr + (((4 + g) ^ rx) << 3));         \
            o[cg][md] = MFMA32(av0, b0.v, o[cg][md]);                          \
            o[cg][md] = MFMA32(av1, b1.v, o[cg][md]);                          \
        }                                                                      \
    }                                                                          \
} while (0)
#endif

#define ATTN_COMPUTE(PAR) do {                                                 \
    unsigned int pk0[2][4], pk1[2][4];                                         \
    for (int mt = 0; mt < 4; ++mt) {                                           \
        const unsigned short* kr = Ks + (PAR) * (64 * 64) + (mt * 16 + cl) * 64; \
        bf16x8 a0 = *(const bf16x8*)(kr + ((g ^ rx) << 3));                    \
        bf16x8 a1 = *(const bf16x8*)(kr + (((4 + g) ^ rx) << 3));              \
        for (int cg = 0; cg < 2; ++cg) {                                       \
            f32x4 z = zero;                                                    \
            z = MFMA32(a0, bq[cg][0], z);                                      \
            z = MFMA32(a1, bq[cg][1], z);                                      \
            float p0 = EXP2F(z[0]), p1 = EXP2F(z[1]);                          \
            float p2 = EXP2F(z[2]), p3 = EXP2F(z[3]);                          \
            l_run[cg] += (p0 + p1) + (p2 + p3);                                \
            pk0[cg][mt] = packrn(p0, p1);                                      \
            pk1[cg][mt] = packrn(p2, p3);                                      \
        }                                                                      \
    }                                                                          \
    ATTN_PV(PAR);                                                              \
} while (0)

    ATTN_ISSUE(0); ATTN_ISSUE(1);
    for (int it = 0; it < 14; ++it) {
        PIPE_BAR(4);
        ATTN_COMPUTE(it & 1);
        END_BAR();
        ATTN_ISSUE(it & 1);
    }
    PIPE_BAR(4);
    ATTN_COMPUTE(0);
    PIPE_BAR(0);
    ATTN_COMPUTE(1);

    for (int cg = 0; cg < 2; ++cg) {
        float l = l_run[cg];
        l += __shfl_xor(l, 16);
        l += __shfl_xor(l, 32);
        const int q = qt * 128 + w * 32 + cg * 16 + cl;
        const size_t pidx = ((size_t)(b * NH + h) * LQ + q) * 4 + ck;
        for (int md = 0; md < 4; ++md)
            *(f32x4*)(OP + pidx * 64 + md * 16 + g * 4) = o[cg][md];
        if (g == 0) Lp[pidx] = l;
    }
}

// ---------------- split-K combine (plain sum; shared implicit max=0) ----------------
__global__ __launch_bounds__(256) void combine(const float* __restrict__ OP,
                                               const float* __restrict__ Lp,
                                               unsigned short* __restrict__ AO) {
    int t = blockIdx.x * 256 + threadIdx.x;      // 524288 threads
    int bhq = t >> 4, dg = (t & 15) * 4;
    float4 L4 = *(const float4*)(Lp + (size_t)bhq * 4);
    float inv = 1.f / (((L4.x + L4.y) + (L4.z + L4.w)));
    float4 acc = make_float4(0.f, 0.f, 0.f, 0.f);
    for (int c = 0; c < 4; ++c) {
        float4 v = *(const float4*)(OP + (size_t)(bhq * 4 + c) * 64 + dg);
        acc.x += v.x; acc.y += v.y; acc.z += v.z; acc.w += v.w;
    }
    int b = bhq >> 13, h = (bhq >> 9) & 15, q = bhq & 511;
    us4 ob;
    ob.x = f2bf(acc.x * inv); ob.y = f2bf(acc.y * inv);
    ob.z = f2bf(acc.z * inv); ob.w = f2bf(acc.w * inv);
    *(us4*)(AO + (size_t)(b * LQ + q) * D_MODEL + h * DH + dg) = ob;
}

// ---------------- launch ----------------
extern "C" void kernel_launch(void* const* d_in, const int* in_sizes, int n_in,
                              void* d_out, int out_size, void* d_ws, size_t ws_size,
                              hipStream_t stream) {
    const float* q_in = (const float*)d_in[0];
    const float* mem  = (const float*)d_in[1];
    const float* Wq = (const float*)d_in[3];
    const float* Wk = (const float*)d_in[4];
    const float* Wv = (const float*)d_in[5];
    const float* Wo = (const float*)d_in[6];
    float* out = (float*)d_out;

    constexpr size_t E_Q = (size_t)BB * LQ * D_MODEL;       // 2,097,152
    constexpr size_t E_M = (size_t)BB * LK * D_MODEL;       // 16,777,216
    constexpr size_t E_W = (size_t)D_MODEL * D_MODEL;       // 1,048,576
    constexpr size_t E_OP = (size_t)BB * NH * LQ * 4 * 64;  // 8,388,608 floats
    constexpr size_t E_L  = (size_t)BB * NH * LQ * 4;       // 131,072 floats

    float* OP = (float*)d_ws;
    float* Lp = OP + E_OP;
    unsigned short* qb   = (unsigned short*)(Lp + E_L);
    unsigned short* memb = qb + E_Q;
    unsigned short* wqb  = memb + E_M;          // Wq|Wk|Wv|Wo contiguous
    unsigned short* wob  = wqb + 3 * E_W;
    unsigned short* Qp   = wob + E_W;
    unsigned short* Kp   = Qp + E_Q;
    unsigned short* Vt   = Kp + E_M;
    unsigned short* AO   = Vt + E_M;

    constexpr int CVT_BLK = (int)((E_Q + E_M + 4 * E_W) / 4 / 256);  // 22528
    cvt_all<<<CVT_BLK, 256, 0, stream>>>(q_in, mem, Wq, Wk, Wv, Wo, qb);

    proj256<<<512, 512, 0, stream>>>(memb, wqb, Kp, Vt);
    proj_q<<<128, 256, 0, stream>>>(qb, wqb, Qp);

    attn<<<dim3(256, 4), 256, 0, stream>>>(Qp, Kp, Vt, OP, Lp);
    combine<<<2048, 256, 0, stream>>>(OP, Lp, AO);

    gemm_o<<<dim3(16, 8), 256, 0, stream>>>(AO, wob, out);
}

// Round 4
// 281.175 us; speedup vs baseline: 1.0824x; 1.0335x over previous
//
#include <hip/hip_runtime.h>

#define D_MODEL 1024
#define NH 16
#define DH 64
#define BB 4
#define LQ 512
#define LK 4096

typedef __attribute__((ext_vector_type(8))) short bf16x8;
typedef __attribute__((ext_vector_type(4))) short bf16x4;
typedef __attribute__((ext_vector_type(4))) float f32x4;
typedef __attribute__((ext_vector_type(4))) unsigned short us4;

union U4 { unsigned int u[2]; bf16x4 v; };
union U8 { unsigned int u[4]; bf16x8 v; };

#define MFMA32(a, b, c) __builtin_amdgcn_mfma_f32_16x16x32_bf16(a, b, c, 0, 0, 0)

#if __has_builtin(__builtin_amdgcn_mfma_f32_16x16x16bf16_1k)
#define HAVE_MFMA16 1
#define MFMA16(a, b, c) __builtin_amdgcn_mfma_f32_16x16x16bf16_1k(a, b, c, 0, 0, 0)
#else
#define HAVE_MFMA16 0
#endif

#if __has_builtin(__builtin_amdgcn_exp2f)
#define EXP2F __builtin_amdgcn_exp2f
#else
__device__ __forceinline__ float EXP2F(float x) { return __expf(x * 0.69314718056f); }
#endif

// Pipeline barriers for the 128^2 kernels (unchanged).
#define PIPE_BAR(KEEP) asm volatile("s_waitcnt vmcnt(" #KEEP ") lgkmcnt(0)\n\ts_barrier" ::: "memory")
#define END_BAR()      asm volatile("s_waitcnt lgkmcnt(0)\n\ts_barrier" ::: "memory")

__device__ __forceinline__ unsigned short f2bf(float f) {
    unsigned int u = __float_as_uint(f);
    u += 0x7fffu + ((u >> 16) & 1u);   // RNE
    return (unsigned short)(u >> 16);
}
__device__ __forceinline__ unsigned int packrn(float a, float b) {
    unsigned int ua = __float_as_uint(a) + 0x8000u;
    unsigned int ub = __float_as_uint(b) + 0x8000u;
    return __builtin_amdgcn_perm(ub, ua, 0x07060302u);
}
__device__ __forceinline__ void gld16(const void* g, void* l) {
    __builtin_amdgcn_global_load_lds(
        (__attribute__((address_space(1))) void*)(g),
        (__attribute__((address_space(3))) void*)(l), 16, 0, 0);
}
__device__ __forceinline__ unsigned int bperm(int srclane4, unsigned int v) {
    return (unsigned int)__builtin_amdgcn_ds_bpermute(srclane4, (int)v);
}

// ---------------- all fp32 -> bf16 converts, one launch ----------------
__global__ __launch_bounds__(256) void cvt_all(const float* __restrict__ q,
                                               const float* __restrict__ mem,
                                               const float* __restrict__ w0, const float* __restrict__ w1,
                                               const float* __restrict__ w2, const float* __restrict__ w3,
                                               unsigned short* __restrict__ dst) {
    constexpr size_t EQ = (size_t)BB * LQ * D_MODEL;
    constexpr size_t EM = (size_t)BB * LK * D_MODEL;
    constexpr size_t EW = (size_t)D_MODEL * D_MODEL;
    constexpr size_t R1 = EQ + EM;
    size_t i = ((size_t)blockIdx.x * 256 + threadIdx.x) * 4;
    const float* s; size_t o;
    if (i < EQ)                { s = q;   o = i; }
    else if (i < R1)           { s = mem; o = i - EQ; }
    else if (i < R1 + EW)      { s = w0;  o = i - R1; }
    else if (i < R1 + 2 * EW)  { s = w1;  o = i - R1 - EW; }
    else if (i < R1 + 3 * EW)  { s = w2;  o = i - R1 - 2 * EW; }
    else                       { s = w3;  o = i - R1 - 3 * EW; }
    float4 v = *(const float4*)(s + o);
    us4 ob;
    ob.x = f2bf(v.x); ob.y = f2bf(v.y); ob.z = f2bf(v.z); ob.w = f2bf(v.w);
    *(us4*)(dst + i) = ob;
}

// -------- shared GEMM-core macros: 128x128 tile, BK=64, 4 waves, dbuf pipeline --------
// (kept for proj_q + gemm_o)
#define GEMM_DECLS                                                                 \
    const int tid = threadIdx.x;                                                   \
    const int w = tid >> 6, lane = tid & 63;                                       \
    const int wr = (w >> 1) * 64, wc = (w & 1) * 64;                               \
    const int srow = lane >> 3, ssw = ((lane & 7) ^ srow) * 8;                     \
    const int fr = lane & 15, g = lane >> 4, frx = fr & 7;                         \
    f32x4 zero = {0.f, 0.f, 0.f, 0.f};                                             \
    f32x4 acc[4][4];                                                               \
    for (int i = 0; i < 4; ++i)                                                    \
        for (int j = 0; j < 4; ++j) acc[i][j] = zero;                              \
    const unsigned short* ga = A + (size_t)(m0 + w * 32 + srow) * 1024 + ssw;      \
    const unsigned short* gb = Bw + (size_t)(n0 + w * 32 + srow) * 1024 + ssw;

#define GEMM_ISSUE(PAR) do {                                                       \
    unsigned short* da = As + (PAR) * (128 * 64) + (w * 32) * 64;                  \
    unsigned short* db = Bs + (PAR) * (128 * 64) + (w * 32) * 64;                  \
    for (int c = 0; c < 4; ++c) {                                                  \
        gld16(ga + (size_t)c * 8 * 1024, da + c * 8 * 64);                         \
        gld16(gb + (size_t)c * 8 * 1024, db + c * 8 * 64);                         \
    }                                                                              \
    ga += 64; gb += 64;                                                            \
} while (0)

#define GEMM_COMPUTE(PAR) do {                                                     \
    const unsigned short* Ap = As + (PAR) * (128 * 64);                            \
    const unsigned short* Bp = Bs + (PAR) * (128 * 64);                            \
    for (int ks = 0; ks < 2; ++ks) {                                               \
        const int fx = ((ks * 4 + g) ^ frx) * 8;                                   \
        bf16x8 af[4], bfr[4];                                                      \
        for (int i = 0; i < 4; ++i) af[i] = *(const bf16x8*)(Ap + (wr + 16 * i + fr) * 64 + fx); \
        for (int j = 0; j < 4; ++j) bfr[j] = *(const bf16x8*)(Bp + (wc + 16 * j + fr) * 64 + fx); \
        for (int i = 0; i < 4; ++i)                                                \
            for (int j = 0; j < 4; ++j)                                            \
                acc[i][j] = MFMA32(af[i], bfr[j], acc[i][j]);                      \
    }                                                                              \
} while (0)

#define GEMM_PIPELINE                                                              \
    GEMM_ISSUE(0); GEMM_ISSUE(1);                                                  \
    for (int it = 0; it < 14; ++it) {                                              \
        PIPE_BAR(8);                                                               \
        GEMM_COMPUTE(it & 1);                                                      \
        END_BAR();                                                                 \
        GEMM_ISSUE(it & 1);                                                        \
    }                                                                              \
    PIPE_BAR(8);                                                                   \
    GEMM_COMPUTE(0);                                                               \
    PIPE_BAR(0);                                                                   \
    GEMM_COMPUTE(1);

// ================== 256x256-tile K/V projection, K=32 windows, 1 barrier/window ==================
// r4: r3's FETCH fix held (50 MB) but phase time stayed ~1540 cyc vs 620 MFMA floor with all
// pipes non-binding -> remaining cost attributed to per-phase sync events. Merge phase pairs:
// per K=32 window: {12 ds_read (next piece, reg ping-pong); 4 gld16 stage; 32 MFMA;
// VW(4); lgkm(0)+barrier}. 2 barriers + 2 VW per 64-K tile (was 4 + 2).
// Ring: 4 slots x [256 rows][32 K] per operand (128 KiB). Window h reads piece h+1
// (slot (h+1)&3), computes piece h, stages piece h+3 (slot (h+3)&3).
// FIFO proof: VW(4)@h drains stage(h-1)=piece h+2 -> barrier -> read at h+1. Overwrite
// of piece h-1's slot at h is 2 barriers after its last ds_read (window h-2). Tail:
// stage while h<=28; VW(0)@29; windows 30,31 bare.
#define SLOT_SH 8192  /* shorts per slot: 256*32 */

#define STAGE2(GB, LB, S, H) do {                                                  \
    const unsigned short* gs_ = (GB) + (size_t)(H) * 32;                           \
    unsigned short* ld_ = (LB) + (S) * SLOT_SH + tid * 8;                          \
    gld16(gs_, ld_);                                                               \
    gld16(gs_ + (size_t)131072, ld_ + 4096);  /* +128 rows / second half */        \
} while (0)

#define RD_A8(DST, SLOT) do {                                                      \
    const unsigned short* Ap_ = As + (size_t)(SLOT) * SLOT_SH + aoff;              \
    _Pragma("unroll")                                                              \
    for (int ii_ = 0; ii_ < 8; ++ii_)                                              \
        DST[ii_] = *(const bf16x8*)(Ap_ + ii_ * 512);                              \
} while (0)

#define RD_B(DST, SLOT) do {                                                       \
    const unsigned short* Bp_ = Bs + (size_t)(SLOT) * SLOT_SH + boff;              \
    _Pragma("unroll")                                                              \
    for (int jj_ = 0; jj_ < 4; ++jj_)                                              \
        DST[jj_] = *(const bf16x8*)(Bp_ + jj_ * 512);                              \
} while (0)

#define MM32(AF, BF) do {                                                          \
    __builtin_amdgcn_s_setprio(1);                                                 \
    _Pragma("unroll")                                                              \
    for (int ii = 0; ii < 8; ++ii) {                                               \
        _Pragma("unroll")                                                          \
        for (int jj = 0; jj < 4; ++jj)                                             \
            acc[ii][jj] = MFMA32(AF[ii], BF[jj], acc[ii][jj]);                     \
    }                                                                              \
    __builtin_amdgcn_s_setprio(0);                                                 \
} while (0)

#define VW(N)  asm volatile("s_waitcnt vmcnt(" #N ")" ::: "memory")
#define PEND() asm volatile("s_waitcnt lgkmcnt(0)\n\ts_barrier" ::: "memory")

// Window h: AFC/BFC = current piece fragments (piece h), AFN/BFN = next (piece h+1).
#define WIN(H, AFC, BFC, AFN, BFN) do {                                            \
    const int sn_ = ((H) + 1) & 3;                                                 \
    RD_A8(AFN, sn_); RD_B(BFN, sn_);                                               \
    STAGE2(gA, As, ((H) + 3) & 3, (H) + 3);                                        \
    STAGE2(gB, Bs, ((H) + 3) & 3, (H) + 3);                                        \
    MM32(AFC, BFC);                                                                \
    VW(4);                                                                         \
    PEND();                                                                        \
} while (0)

__global__ __launch_bounds__(512, 2) void proj256(const unsigned short* __restrict__ memb,
                                                  const unsigned short* __restrict__ W,  // wqb base: Wq|Wk|Wv|Wo
                                                  unsigned short* __restrict__ Kp,
                                                  unsigned short* __restrict__ Vt) {
    __shared__ alignas(16) unsigned short As[4 * SLOT_SH];   // 64 KiB
    __shared__ alignas(16) unsigned short Bs[4 * SLOT_SH];   // 64 KiB
    // 512 blocks = 2 rounds of 256. Per XCD-round: 32 blocks = 4 A-tiles x 8 strips
    // (nt 0..3 x {K,V}) -> A-tile shared by 8 concurrent blocks on one XCD (FETCH: 136->50MB).
    const int x = blockIdx.x;
    const int xcd = x & 7, s = x >> 3;            // HW dispatch: block x -> XCD x%8
    const int rnd = s >> 5, i5 = s & 31;          // 2 rounds x 32 concurrent slots
    const int mt = xcd * 8 + rnd * 4 + (i5 >> 3); // 4 A-tiles per XCD-round (disjoint across XCDs)
    const int strip = i5 & 7;
    const int isV = strip >> 2, nt = strip & 3;
    const int m0 = mt * 256, n0 = nt * 256;
    const unsigned short* Bw = W + ((size_t)(1 + isV) << 20);  // Wk / Wv

    const int tid = threadIdx.x;
    const int lane = tid & 63, wid = tid >> 6;
    const int wm = wid >> 2, wn = wid & 3;
    const int fr = lane & 15, g = lane >> 4;
    const int sfr = (fr >> 1) & 3;                                   // swizzle bits for frag rows
    const int aoff = (wm * 128 + fr) * 32 + ((g ^ sfr) << 3);        // shorts into an A slot
    const int boff = (wn * 64 + fr) * 32 + ((g ^ sfr) << 3);         // shorts into a B slot

    f32x4 zero = {0.f, 0.f, 0.f, 0.f};
    f32x4 acc[8][4];
#pragma unroll
    for (int i = 0; i < 8; ++i)
#pragma unroll
        for (int j = 0; j < 4; ++j) acc[i][j] = zero;

    // staging addressing: thread covers rows (tid>>2) and (tid>>2)+128 of a piece,
    // 8-elem chunk (tid&3), with the inverse swizzle applied on the GLOBAL side.
    const int srow = tid >> 2;
    const int scg = (tid & 3) ^ ((tid >> 3) & 3);
    const unsigned short* gA = memb + (size_t)(m0 + srow) * 1024 + scg * 8;
    const unsigned short* gB = Bw + (size_t)(n0 + srow) * 1024 + scg * 8;

    bf16x8 afA[8], afB[8], bfA[4], bfB[4];

    // prologue: stage pieces 0,1,2; drain 0,1; preload piece 0 fragments.
    STAGE2(gA, As, 0, 0); STAGE2(gB, Bs, 0, 0);
    STAGE2(gA, As, 1, 1); STAGE2(gB, Bs, 1, 1);
    STAGE2(gA, As, 2, 2); STAGE2(gB, Bs, 2, 2);
    VW(4);
    asm volatile("s_barrier" ::: "memory");
    RD_A8(afA, 0); RD_B(bfA, 0);                  // compiler inserts lgkm before first MFMA

    for (int u = 0; u < 14; ++u) {                // windows h = 0..27
        WIN(2 * u,     afA, bfA, afB, bfB);
        WIN(2 * u + 1, afB, bfB, afA, bfA);
    }
    // h=28: stage piece 31; VW(4) drains piece 30.
    WIN(28, afA, bfA, afB, bfB);
    // h=29: no stage; VW(0) drains piece 31.
    RD_A8(afA, 2); RD_B(bfA, 2);                  // piece 30 (slot 2)
    MM32(afB, bfB);
    VW(0);
    PEND();
    // h=30: read piece 31 (slot 3); no stage/VW.
    RD_A8(afB, 3); RD_B(bfB, 3);
    MM32(afA, bfA);
    PEND();
    // h=31: compute only.
    MM32(afB, bfB);

    // epilogue (same verified C/D mapping; V-path vectorized: r=0..3 -> t contiguous)
    const int cl = fr;
    if (!isV) {
#pragma unroll
        for (int i = 0; i < 8; ++i)
#pragma unroll
            for (int j = 0; j < 4; ++j)
#pragma unroll
                for (int r = 0; r < 4; ++r) {
                    int m = m0 + wm * 128 + 16 * i + g * 4 + r;
                    int n = n0 + wn * 64 + 16 * j + cl;
                    Kp[(size_t)m * 1024 + n] = f2bf(acc[i][j][r]);
                }
    } else {
#pragma unroll
        for (int i = 0; i < 8; ++i)
#pragma unroll
            for (int j = 0; j < 4; ++j) {
                int m = m0 + wm * 128 + 16 * i + g * 4;   // r=0 base; +r stays in same b
                int n = n0 + wn * 64 + 16 * j + cl;
                int b = m >> 12, tt2 = m & 4095;
                int h = n >> 6, d = n & 63;
                us4 ov;
                ov.x = f2bf(acc[i][j][0]); ov.y = f2bf(acc[i][j][1]);
                ov.z = f2bf(acc[i][j][2]); ov.w = f2bf(acc[i][j][3]);
                *(us4*)(Vt + ((size_t)(b * NH + h) * DH + d) * LK + tt2) = ov;
            }
    }
}

// ---------------- Q projection (small: 4.3 GF) on the 128^2 structure ----------------
__global__ __launch_bounds__(256, 2) void proj_q(const unsigned short* __restrict__ qb,
                                                 const unsigned short* __restrict__ W,
                                                 unsigned short* __restrict__ Qp) {
    __shared__ alignas(16) unsigned short As[2 * 128 * 64];
    __shared__ alignas(16) unsigned short Bs[2 * 128 * 64];
    const int x = blockIdx.x;            // 128 blocks: 16 mt x 8 nt
    const int mt = x & 15, nt = x >> 4;
    const unsigned short* A = qb;
    const unsigned short* Bw = W;        // Wq
    const int m0 = mt * 128, n0 = nt * 128;

    GEMM_DECLS
    GEMM_PIPELINE

    const int cl = lane & 15;
    const float QSCALE = 0.18033688011112042f;  // 0.125 * log2(e)
    for (int i = 0; i < 4; ++i)
        for (int j = 0; j < 4; ++j)
            for (int r = 0; r < 4; ++r) {
                int m = m0 + wr + 16 * i + g * 4 + r;
                int n = n0 + wc + 16 * j + cl;
                Qp[(size_t)m * 1024 + n] = f2bf(acc[i][j][r] * QSCALE);
            }
}

// ---------------- output projection (bf16 A, fp32 out) ----------------
__global__ __launch_bounds__(256, 2) void gemm_o(const unsigned short* __restrict__ A,
                                                 const unsigned short* __restrict__ Bw,
                                                 float* __restrict__ C) {
    __shared__ alignas(16) unsigned short As[2 * 128 * 64];
    __shared__ alignas(16) unsigned short Bs[2 * 128 * 64];
    const int m0 = blockIdx.x * 128, n0 = blockIdx.y * 128;

    GEMM_DECLS
    GEMM_PIPELINE

    const int cl = lane & 15;
    for (int i = 0; i < 4; ++i)
        for (int j = 0; j < 4; ++j)
            for (int r = 0; r < 4; ++r) {
                int m = m0 + wr + 16 * i + g * 4 + r;
                int n = n0 + wc + 16 * j + cl;
                C[(size_t)m * 1024 + n] = acc[i][j][r];
            }
}

// ---------------- flash attention, split-K=4, 32 q/wave, dbuf pipeline ----------------
__global__ __launch_bounds__(256, 4) void attn(const unsigned short* __restrict__ Qp,
                                               const unsigned short* __restrict__ Kp,
                                               const unsigned short* __restrict__ Vt,
                                               float* __restrict__ OP, float* __restrict__ Lp) {
    __shared__ alignas(16) unsigned short Ks[2 * 64 * 64];
    __shared__ alignas(16) unsigned short Vs[2 * 64 * 64];
    const int tid = threadIdx.x, w = tid >> 6, lane = tid & 63;
    const int gid = blockIdx.x, qt = blockIdx.y;
    const int h = gid & 15, bck = gid >> 4;
    const int b = bck >> 2, ck = bck & 3;
    const int cl = lane & 15, g = lane >> 4;
    const int rx = cl & 7;

    // Q^T B-operand fragments for both q-groups (Q pre-scaled by 0.125*log2e)
    bf16x8 bq[2][2];
    for (int cg = 0; cg < 2; ++cg) {
        const size_t qrow = (size_t)(b * LQ + qt * 128 + w * 32 + cg * 16 + cl) * D_MODEL + h * DH;
        bq[cg][0] = *(const bf16x8*)(Qp + qrow + g * 8);
        bq[cg][1] = *(const bf16x8*)(Qp + qrow + 32 + g * 8);
    }

    float l_run[2] = {0.f, 0.f};
    f32x4 zero = {0.f, 0.f, 0.f, 0.f};
    f32x4 o[2][4];
    for (int cg = 0; cg < 2; ++cg)
        for (int i = 0; i < 4; ++i) o[cg][i] = zero;

    const int srow = lane >> 3;
    const int ssw = ((lane & 7) ^ srow) * 8;
    const int k0 = ck * (LK / 4);
    const unsigned short* kp = Kp + (size_t)b * LK * D_MODEL + h * DH +
                               (size_t)(k0 + w * 16 + srow) * D_MODEL + ssw;
    const unsigned short* vp = Vt + (size_t)(b * NH + h) * DH * LK +
                               (size_t)(w * 16 + srow) * LK + k0 + ssw;

#define ATTN_ISSUE(PAR) do {                                                   \
    unsigned short* kd = Ks + (PAR) * (64 * 64) + (w * 16) * 64;               \
    unsigned short* vd = Vs + (PAR) * (64 * 64) + (w * 16) * 64;               \
    gld16(kp, kd); gld16(kp + (size_t)8 * D_MODEL, kd + 8 * 64);               \
    gld16(vp, vd); gld16(vp + (size_t)8 * LK, vd + 8 * 64);                    \
    kp += (size_t)64 * D_MODEL; vp += 64;                                      \
} while (0)

#if HAVE_MFMA16
#define ATTN_PV(PAR) do {                                                      \
    for (int md = 0; md < 4; ++md) {                                           \
        const unsigned short* vr = Vs + (PAR) * (64 * 64) + (md * 16 + cl) * 64; \
        for (int ksv = 0; ksv < 4; ++ksv) {                                    \
            bf16x4 av = *(const bf16x4*)(vr + (((2 * ksv + (g >> 1)) ^ rx) << 3) + ((g & 1) << 2)); \
            for (int cg = 0; cg < 2; ++cg) {                                   \
                U4 pb; pb.u[0] = pk0[cg][ksv]; pb.u[1] = pk1[cg][ksv];         \
                o[cg][md] = MFMA16(av, pb.v, o[cg][md]);                       \
            }                                                                  \
        }                                                                      \
    }                                                                          \
} while (0)
#else
#define ATTN_PV(PAR) do {                                                      \
    for (int cg = 0; cg < 2; ++cg) {                                           \
        const int selA = ((((g & 1) << 5) | cl)) << 2;                         \
        const int selB = selA + 64;                                            \
        const int hi = g >> 1;                                                 \
        unsigned int ax0 = bperm(selA, pk0[cg][0]), ax1 = bperm(selA, pk0[cg][1]); \
        unsigned int ay0 = bperm(selA, pk1[cg][0]), ay1 = bperm(selA, pk1[cg][1]); \
        unsigned int bx0 = bperm(selB, pk0[cg][0]), bx1 = bperm(selB, pk0[cg][1]); \
        unsigned int by0 = bperm(selB, pk1[cg][0]), by1 = bperm(selB, pk1[cg][1]); \
        U8 b0;                                                                 \
        b0.u[0] = hi ? ax1 : ax0; b0.u[1] = hi ? ay1 : ay0;                    \
        b0.u[2] = hi ? bx1 : bx0; b0.u[3] = hi ? by1 : by0;                    \
        unsigned int cx0 = bperm(selA, pk0[cg][2]), cx1 = bperm(selA, pk0[cg][3]); \
        unsigned int cy0 = bperm(selA, pk1[cg][2]), cy1 = bperm(selA, pk1[cg][3]); \
        unsigned int dx0 = bperm(selB, pk0[cg][2]), dx1 = bperm(selB, pk0[cg][3]); \
        unsigned int dy0 = bperm(selB, pk1[cg][2]), dy1 = bperm(selB, pk1[cg][3]); \
        U8 b1;                                                                 \
        b1.u[0] = hi ? cx1 : cx0; b1.u[1] = hi ? cy1 : cy0;                    \
        b1.u[2] = hi ? dx1 : dx0; b1.u[3] = hi ? dy1 : dy0;                    \
        for (int md = 0; md < 4; ++md) {                                       \
            const unsigned short* vr = Vs + (PAR) * (64 * 64) + (md * 16 + cl) * 64; \
            bf16x8 av0 = *(const bf16x8*)(vr + ((g ^ rx) << 3));               \
            bf16x8 av1 = *(const bf16x8*)(vr + (((4 + g) ^ rx) << 3));         \
            o[cg][md] = MFMA32(av0, b0.v, o[cg][md]);                          \
            o[cg][md] = MFMA32(av1, b1.v, o[cg][md]);                          \
        }                                                                      \
    }                                                                          \
} while (0)
#endif

#define ATTN_COMPUTE(PAR) do {                                                 \
    unsigned int pk0[2][4], pk1[2][4];                                         \
    for (int mt = 0; mt < 4; ++mt) {                                           \
        const unsigned short* kr = Ks + (PAR) * (64 * 64) + (mt * 16 + cl) * 64; \
        bf16x8 a0 = *(const bf16x8*)(kr + ((g ^ rx) << 3));                    \
        bf16x8 a1 = *(const bf16x8*)(kr + (((4 + g) ^ rx) << 3));              \
        for (int cg = 0; cg < 2; ++cg) {                                       \
            f32x4 z = zero;                                                    \
            z = MFMA32(a0, bq[cg][0], z);                                      \
            z = MFMA32(a1, bq[cg][1], z);                                      \
            float p0 = EXP2F(z[0]), p1 = EXP2F(z[1]);                          \
            float p2 = EXP2F(z[2]), p3 = EXP2F(z[3]);                          \
            l_run[cg] += (p0 + p1) + (p2 + p3);                                \
            pk0[cg][mt] = packrn(p0, p1);                                      \
            pk1[cg][mt] = packrn(p2, p3);                                      \
        }                                                                      \
    }                                                                          \
    ATTN_PV(PAR);                                                              \
} while (0)

    ATTN_ISSUE(0); ATTN_ISSUE(1);
    for (int it = 0; it < 14; ++it) {
        PIPE_BAR(4);
        ATTN_COMPUTE(it & 1);
        END_BAR();
        ATTN_ISSUE(it & 1);
    }
    PIPE_BAR(4);
    ATTN_COMPUTE(0);
    PIPE_BAR(0);
    ATTN_COMPUTE(1);

    for (int cg = 0; cg < 2; ++cg) {
        float l = l_run[cg];
        l += __shfl_xor(l, 16);
        l += __shfl_xor(l, 32);
        const int q = qt * 128 + w * 32 + cg * 16 + cl;
        const size_t pidx = ((size_t)(b * NH + h) * LQ + q) * 4 + ck;
        for (int md = 0; md < 4; ++md)
            *(f32x4*)(OP + pidx * 64 + md * 16 + g * 4) = o[cg][md];
        if (g == 0) Lp[pidx] = l;
    }
}

// ---------------- split-K combine (plain sum; shared implicit max=0) ----------------
__global__ __launch_bounds__(256) void combine(const float* __restrict__ OP,
                                               const float* __restrict__ Lp,
                                               unsigned short* __restrict__ AO) {
    int t = blockIdx.x * 256 + threadIdx.x;      // 524288 threads
    int bhq = t >> 4, dg = (t & 15) * 4;
    float4 L4 = *(const float4*)(Lp + (size_t)bhq * 4);
    float inv = 1.f / (((L4.x + L4.y) + (L4.z + L4.w)));
    float4 acc = make_float4(0.f, 0.f, 0.f, 0.f);
    for (int c = 0; c < 4; ++c) {
        float4 v = *(const float4*)(OP + (size_t)(bhq * 4 + c) * 64 + dg);
        acc.x += v.x; acc.y += v.y; acc.z += v.z; acc.w += v.w;
    }
    int b = bhq >> 13, h = (bhq >> 9) & 15, q = bhq & 511;
    us4 ob;
    ob.x = f2bf(acc.x * inv); ob.y = f2bf(acc.y * inv);
    ob.z = f2bf(acc.z * inv); ob.w = f2bf(acc.w * inv);
    *(us4*)(AO + (size_t)(b * LQ + q) * D_MODEL + h * DH + dg) = ob;
}

// ---------------- launch ----------------
extern "C" void kernel_launch(void* const* d_in, const int* in_sizes, int n_in,
                              void* d_out, int out_size, void* d_ws, size_t ws_size,
                              hipStream_t stream) {
    const float* q_in = (const float*)d_in[0];
    const float* mem  = (const float*)d_in[1];
    const float* Wq = (const float*)d_in[3];
    const float* Wk = (const float*)d_in[4];
    const float* Wv = (const float*)d_in[5];
    const float* Wo = (const float*)d_in[6];
    float* out = (float*)d_out;

    constexpr size_t E_Q = (size_t)BB * LQ * D_MODEL;       // 2,097,152
    constexpr size_t E_M = (size_t)BB * LK * D_MODEL;       // 16,777,216
    constexpr size_t E_W = (size_t)D_MODEL * D_MODEL;       // 1,048,576
    constexpr size_t E_OP = (size_t)BB * NH * LQ * 4 * 64;  // 8,388,608 floats
    constexpr size_t E_L  = (size_t)BB * NH * LQ * 4;       // 131,072 floats

    float* OP = (float*)d_ws;
    float* Lp = OP + E_OP;
    unsigned short* qb   = (unsigned short*)(Lp + E_L);
    unsigned short* memb = qb + E_Q;
    unsigned short* wqb  = memb + E_M;          // Wq|Wk|Wv|Wo contiguous
    unsigned short* wob  = wqb + 3 * E_W;
    unsigned short* Qp   = wob + E_W;
    unsigned short* Kp   = Qp + E_Q;
    unsigned short* Vt   = Kp + E_M;
    unsigned short* AO   = Vt + E_M;

    constexpr int CVT_BLK = (int)((E_Q + E_M + 4 * E_W) / 4 / 256);  // 22528
    cvt_all<<<CVT_BLK, 256, 0, stream>>>(q_in, mem, Wq, Wk, Wv, Wo, qb);

    proj256<<<512, 512, 0, stream>>>(memb, wqb, Kp, Vt);
    proj_q<<<128, 256, 0, stream>>>(qb, wqb, Qp);

    attn<<<dim3(256, 4), 256, 0, stream>>>(Qp, Kp, Vt, OP, Lp);
    combine<<<2048, 256, 0, stream>>>(OP, Lp, AO);

    gemm_o<<<dim3(16, 8), 256, 0, stream>>>(AO, wob, out);
}